// Round 2
// baseline (509.812 us; speedup 1.0000x reference)
//
#include <hip/hip_runtime.h>

#define B_  8
#define S_  4096
#define D_  768
#define H_  12
#define M_  (B_ * S_)      // 32768
#define NQKV_ 2304         // 3*D

typedef unsigned short u16;
typedef __attribute__((ext_vector_type(4))) float  f32x4;
typedef __attribute__((ext_vector_type(8))) __bf16 bf16x8;
typedef __attribute__((ext_vector_type(4))) u16    u16x4;

#define GAS __attribute__((address_space(1)))
#define LAS __attribute__((address_space(3)))

__device__ __forceinline__ u16 f2bf(float f) {
    unsigned u = __float_as_uint(f);
    u += 0x7FFF + ((u >> 16) & 1);          // round-to-nearest-even
    return (u16)(u >> 16);
}
__device__ __forceinline__ float bf2f(u16 h) {
    return __uint_as_float(((unsigned)h) << 16);
}

__device__ __forceinline__ void gload_lds16(const void* g, void* l) {
    __builtin_amdgcn_global_load_lds((const GAS void*)g, (LAS void*)l, 16, 0, 0);
}

// ---------------- cast x (f32 -> bf16) ----------------
__global__ __launch_bounds__(256) void castx_kernel(const float* __restrict__ x,
                                                    u16* __restrict__ xb) {
    const int i = blockIdx.x * 256 + threadIdx.x;
    const float4 v = ((const float4*)x)[i];
    u16x4 o;
    o.x = f2bf(v.x); o.y = f2bf(v.y); o.z = f2bf(v.z); o.w = f2bf(v.w);
    ((u16x4*)xb)[i] = o;
}

// ---------------- weight transpose+cast: W[k][n] f32 -> Wb[n][k] bf16 ----------------
__global__ __launch_bounds__(256) void wtrans_kernel(const float* __restrict__ Wq,
                                                     const float* __restrict__ Wk,
                                                     const float* __restrict__ Wv,
                                                     const float* __restrict__ Wo,
                                                     u16* __restrict__ Wb) {
    const float* W = (blockIdx.z == 0) ? Wq : (blockIdx.z == 1) ? Wk
                   : (blockIdx.z == 2) ? Wv : Wo;
    u16* O = Wb + (size_t)blockIdx.z * D_ * D_;
    __shared__ float tile[32][33];
    const int tx = threadIdx.x & 31, ty = threadIdx.x >> 5;  // 32x8
    const int k0 = blockIdx.y * 32, n0 = blockIdx.x * 32;
#pragma unroll
    for (int j = 0; j < 4; j++)
        tile[ty + j * 8][tx] = W[(size_t)(k0 + ty + j * 8) * D_ + n0 + tx];
    __syncthreads();
#pragma unroll
    for (int j = 0; j < 4; j++)
        O[(size_t)(n0 + ty + j * 8) * D_ + k0 + tx] = f2bf(tile[tx][ty + j * 8]);
}

// ---------------- 128x128 bf16 MFMA GEMM (m97 structure) ----------------
// A: [M][768] bf16 row-major.  Bt: weight [n][k] bf16 (transposed).
// MODE 0: QKV — blockIdx.x in [0,18): widx = bx/6 selects Wq/Wk/Wv, out bf16 [M][2304], +bias
// MODE 1: OUT — blockIdx.x in [0,6): Wo, out f32 [M][768], + bo + x residual
template <int MODE>
__global__ __launch_bounds__(256) void gemm_kernel(
    const u16* __restrict__ A, const u16* __restrict__ Wb,
    const float* __restrict__ b0, const float* __restrict__ b1,
    const float* __restrict__ b2,
    u16* __restrict__ outb, float* __restrict__ outf,
    const float* __restrict__ xres) {
    __shared__ u16 Als[128 * 32];
    __shared__ u16 Bls[128 * 32];

    const int t = threadIdx.x;
    const int w = t >> 6, l = t & 63;
    const int m0 = blockIdx.y * 128;
    int widx, nloc;
    if (MODE == 0) { widx = blockIdx.x / 6; nloc = blockIdx.x % 6; }
    else           { widx = 3;              nloc = blockIdx.x;     }
    const int n0 = nloc * 128;
    const u16* Bt = Wb + (size_t)widx * (D_ * D_);
    const float* bias = (MODE == 0) ? (widx == 0 ? b0 : widx == 1 ? b1 : b2) : b0;

    // staging coords: thread t covers row t/4 (and +64), 16B chunk (t&3)
    const int srow  = t >> 2;
    const int sbyte = (t & 3) * 16;
    const char* Ag = (const char*)(A  + (size_t)(m0 + srow) * D_) + sbyte;
    const char* Bg = (const char*)(Bt + (size_t)(n0 + srow) * D_) + sbyte;
    char* Al = (char*)Als + w * 1024;   // wave-uniform LDS dest base
    char* Bl = (char*)Bls + w * 1024;

    f32x4 acc[4][4];
#pragma unroll
    for (int i = 0; i < 4; i++)
#pragma unroll
        for (int j = 0; j < 4; j++) acc[i][j] = (f32x4){0.f, 0.f, 0.f, 0.f};

    const int mbase = (w >> 1) * 64, nbase = (w & 1) * 64;
    const int fr   = l & 15;           // fragment row/col within 16
    const int koff = (l >> 4) * 8;     // k-group offset (elems)

    for (int kt = 0; kt < D_; kt += 32) {
        const int cb = kt * 2;         // BYTE offset along K (kt elems * 2B)
        gload_lds16(Ag + cb,                 Al);
        gload_lds16(Ag + cb + 64 * (D_ * 2), Al + 4096);
        gload_lds16(Bg + cb,                 Bl);
        gload_lds16(Bg + cb + 64 * (D_ * 2), Bl + 4096);
        __syncthreads();

        bf16x8 af[4], bf[4];
#pragma unroll
        for (int mi = 0; mi < 4; mi++)
            af[mi] = *(const bf16x8*)(Als + (mbase + mi * 16 + fr) * 32 + koff);
#pragma unroll
        for (int ni = 0; ni < 4; ni++)
            bf[ni] = *(const bf16x8*)(Bls + (nbase + ni * 16 + fr) * 32 + koff);
#pragma unroll
        for (int mi = 0; mi < 4; mi++)
#pragma unroll
            for (int ni = 0; ni < 4; ni++)
                acc[mi][ni] = __builtin_amdgcn_mfma_f32_16x16x32_bf16(
                    af[mi], bf[ni], acc[mi][ni], 0, 0, 0);
        __syncthreads();
    }

    // epilogue: C[row=(l>>4)*4+r + mi*16 + mbase][col=fr + ni*16 + nbase]
    const int crow0 = m0 + mbase + (l >> 4) * 4;
    const int ccol0 = nbase + fr;
    if (MODE == 0) {
        const int cbase = widx * D_ + n0;
#pragma unroll
        for (int mi = 0; mi < 4; mi++)
#pragma unroll
            for (int ni = 0; ni < 4; ni++) {
                const int cc = ccol0 + ni * 16;
                const float bv = bias[n0 + cc];
#pragma unroll
                for (int r = 0; r < 4; r++)
                    outb[(size_t)(crow0 + mi * 16 + r) * NQKV_ + cbase + cc] =
                        f2bf(acc[mi][ni][r] + bv);
            }
    } else {
#pragma unroll
        for (int mi = 0; mi < 4; mi++)
#pragma unroll
            for (int ni = 0; ni < 4; ni++) {
                const int cc = n0 + ccol0 + ni * 16;
                const float bv = bias[cc];
#pragma unroll
                for (int r = 0; r < 4; r++) {
                    const size_t idx = (size_t)(crow0 + mi * 16 + r) * D_ + cc;
                    outf[idx] = acc[mi][ni][r] + bv + xres[idx];
                }
            }
    }
}

// ---------------- local attention: one wave per (b,s,h) ----------------
__global__ __launch_bounds__(256) void attn_kernel(const u16* __restrict__ QKV,
                                                   const float* __restrict__ bk,
                                                   const float* __restrict__ bv,
                                                   u16* __restrict__ att) {
    const int gw = blockIdx.x * 4 + (threadIdx.x >> 6);
    const int l  = threadIdx.x & 63;
    const int h  = gw % H_;
    const int m  = gw / H_;
    const int s  = m & (S_ - 1);
    const u16* base = QKV + (size_t)m * NQKV_;
    const int hd = h * 64 + l;

    const float q = bf2f(base[hd]);
    float sc[5];
#pragma unroll
    for (int i = 0; i < 5; i++) {
        const int sp = s + i - 2;
        const float kd = (sp >= 0 && sp < S_)
                             ? bf2f(base[(i - 2) * NQKV_ + D_ + hd])
                             : bk[hd];
        float p = q * kd;
#pragma unroll
        for (int off = 32; off > 0; off >>= 1) p += __shfl_xor(p, off, 64);
        sc[i] = p * 0.125f;   // / sqrt(64)
    }
    float mx = sc[0];
#pragma unroll
    for (int i = 1; i < 5; i++) mx = fmaxf(mx, sc[i]);
    float e[5], sum = 0.f;
#pragma unroll
    for (int i = 0; i < 5; i++) { e[i] = __expf(sc[i] - mx); sum += e[i]; }
    const float inv = 1.f / sum;
    float o = 0.f;
#pragma unroll
    for (int i = 0; i < 5; i++) {
        const int sp = s + i - 2;
        const float vd = (sp >= 0 && sp < S_)
                             ? bf2f(base[(i - 2) * NQKV_ + 2 * D_ + hd])
                             : bv[hd];
        o += e[i] * inv * vd;
    }
    att[(size_t)m * D_ + hd] = f2bf(o);
}

// ---------------- LayerNorm over rows of 768 ----------------
__global__ __launch_bounds__(256) void ln_kernel(const float* __restrict__ Y,
                                                 const float* __restrict__ gamma,
                                                 const float* __restrict__ beta,
                                                 float* __restrict__ out) {
    const int row = blockIdx.x;
    const float* r = Y + (size_t)row * D_;
    const int t = threadIdx.x;
    const float v0 = r[t], v1 = r[t + 256], v2 = r[t + 512];
    float s  = v0 + v1 + v2;
    float s2 = v0 * v0 + v1 * v1 + v2 * v2;
#pragma unroll
    for (int off = 32; off > 0; off >>= 1) {
        s  += __shfl_xor(s,  off, 64);
        s2 += __shfl_xor(s2, off, 64);
    }
    __shared__ float red[8];
    const int w = t >> 6, l = t & 63;
    if (l == 0) { red[w] = s; red[4 + w] = s2; }
    __syncthreads();
    s  = red[0] + red[1] + red[2] + red[3];
    s2 = red[4] + red[5] + red[6] + red[7];
    const float mu  = s * (1.f / 768.f);
    const float var = s2 * (1.f / 768.f) - mu * mu;
    const float inv = rsqrtf(var + 1e-5f);
    float* o = out + (size_t)row * D_;
    o[t]       = (v0 - mu) * inv * gamma[t]       + beta[t];
    o[t + 256] = (v1 - mu) * inv * gamma[t + 256] + beta[t + 256];
    o[t + 512] = (v2 - mu) * inv * gamma[t + 512] + beta[t + 512];
}

extern "C" void kernel_launch(void* const* d_in, const int* in_sizes, int n_in,
                              void* d_out, int out_size, void* d_ws, size_t ws_size,
                              hipStream_t stream) {
    const float* x     = (const float*)d_in[0];
    const float* Wq    = (const float*)d_in[1];
    const float* bq    = (const float*)d_in[2];
    const float* Wk    = (const float*)d_in[3];
    const float* bk    = (const float*)d_in[4];
    const float* Wv    = (const float*)d_in[5];
    const float* bv    = (const float*)d_in[6];
    const float* Wo    = (const float*)d_in[7];
    const float* bo    = (const float*)d_in[8];
    const float* gamma = (const float*)d_in[9];
    const float* beta  = (const float*)d_in[10];

    char* ws = (char*)d_ws;
    // layout: Wb (4x768x768 bf16) | xb/att (M*768 bf16) | QKV (M*2304 bf16, reused as y' f32)
    u16*   Wb  = (u16*)ws;                                  //  4,718,592 B
    u16*   xb  = (u16*)(ws + 4718592);                      // 50,331,648 B
    u16*   QKV = (u16*)(ws + 4718592 + 50331648);           // 150,994,944 B
    float* yp  = (float*)QKV;                               // reuse (100 MB <= 151 MB)
    u16*   att = xb;                                        // reuse after QKV GEMM

    castx_kernel<<<(M_ * D_) / (256 * 4), 256, 0, stream>>>(x, xb);
    wtrans_kernel<<<dim3(24, 24, 4), 256, 0, stream>>>(Wq, Wk, Wv, Wo, Wb);
    gemm_kernel<0><<<dim3(18, M_ / 128), 256, 0, stream>>>(xb, Wb, bq, bk, bv,
                                                           QKV, nullptr, nullptr);
    attn_kernel<<<(M_ * H_) / 4, 256, 0, stream>>>(QKV, bk, bv, att);
    gemm_kernel<1><<<dim3(6, M_ / 128), 256, 0, stream>>>(att, Wb, bo, nullptr, nullptr,
                                                          nullptr, yp, x);
    ln_kernel<<<M_, 256, 0, stream>>>(yp, gamma, beta, (float*)d_out);
}

// Round 3
// 355.182 us; speedup vs baseline: 1.4354x; 1.4354x over previous
//
#include <hip/hip_runtime.h>

#define B_  8
#define S_  4096
#define D_  768
#define H_  12
#define M_  (B_ * S_)      // 32768
#define NQKV_ 2304         // 3*D

typedef unsigned short u16;
typedef __attribute__((ext_vector_type(4))) float  f32x4;
typedef __attribute__((ext_vector_type(8))) __bf16 bf16x8;
typedef __attribute__((ext_vector_type(4))) u16    u16x4;

#define GAS __attribute__((address_space(1)))
#define LAS __attribute__((address_space(3)))

__device__ __forceinline__ u16 f2bf(float f) {
    unsigned u = __float_as_uint(f);
    u += 0x7FFF + ((u >> 16) & 1);          // round-to-nearest-even
    return (u16)(u >> 16);
}
__device__ __forceinline__ float bf2f(u16 h) {
    return __uint_as_float(((unsigned)h) << 16);
}

__device__ __forceinline__ void gload_lds16(const void* g, void* l) {
    __builtin_amdgcn_global_load_lds((const GAS void*)g, (LAS void*)l, 16, 0, 0);
}

// bijective XCD swizzle (nwg % 8 == 0): each XCD gets a contiguous work chunk
__device__ __forceinline__ int xcd_swz(int bid, int nwg) {
    return (bid & 7) * (nwg >> 3) + (bid >> 3);
}

// ---------------- cast x (f32 -> bf16) ----------------
__global__ __launch_bounds__(256) void castx_kernel(const float* __restrict__ x,
                                                    u16* __restrict__ xb) {
    const int i = blockIdx.x * 256 + threadIdx.x;
    const float4 v = ((const float4*)x)[i];
    u16x4 o;
    o.x = f2bf(v.x); o.y = f2bf(v.y); o.z = f2bf(v.z); o.w = f2bf(v.w);
    ((u16x4*)xb)[i] = o;
}

// ---------------- weight transpose+cast: W[k][n] f32 -> Wb[n][k] bf16 ----------------
__global__ __launch_bounds__(256) void wtrans_kernel(const float* __restrict__ Wq,
                                                     const float* __restrict__ Wk,
                                                     const float* __restrict__ Wv,
                                                     const float* __restrict__ Wo,
                                                     u16* __restrict__ Wb) {
    const float* W = (blockIdx.z == 0) ? Wq : (blockIdx.z == 1) ? Wk
                   : (blockIdx.z == 2) ? Wv : Wo;
    u16* O = Wb + (size_t)blockIdx.z * D_ * D_;
    __shared__ float tile[32][33];
    const int tx = threadIdx.x & 31, ty = threadIdx.x >> 5;  // 32x8
    const int k0 = blockIdx.y * 32, n0 = blockIdx.x * 32;
#pragma unroll
    for (int j = 0; j < 4; j++)
        tile[ty + j * 8][tx] = W[(size_t)(k0 + ty + j * 8) * D_ + n0 + tx];
    __syncthreads();
#pragma unroll
    for (int j = 0; j < 4; j++)
        O[(size_t)(n0 + ty + j * 8) * D_ + k0 + tx] = f2bf(tile[tx][ty + j * 8]);
}

// ---------------- 128x128 bf16 MFMA GEMM (m97 structure, 1D grid + XCD swizzle) ----------------
// A: [M][768] bf16 row-major.  Bt: weight [n][k] bf16 (transposed).
// MODE 0: QKV — work = by*18 + (widx*6 + nloc), out bf16 [M][2304], +bias
// MODE 1: OUT — work = by*6 + nloc, Wo, out f32 [M][768], + bo + x residual
template <int MODE>
__global__ __launch_bounds__(256) void gemm_kernel(
    const u16* __restrict__ A, const u16* __restrict__ Wb,
    const float* __restrict__ b0, const float* __restrict__ b1,
    const float* __restrict__ b2,
    u16* __restrict__ outb, float* __restrict__ outf,
    const float* __restrict__ xres) {
    __shared__ u16 Als[128 * 32];
    __shared__ u16 Bls[128 * 32];

    const int t = threadIdx.x;
    const int w = t >> 6, l = t & 63;
    const int NX = (MODE == 0) ? 18 : 6;
    const int work = xcd_swz(blockIdx.x, gridDim.x);
    const int bx = work % NX;
    const int m0 = (work / NX) * 128;
    int widx, nloc;
    if (MODE == 0) { widx = bx / 6; nloc = bx % 6; }
    else           { widx = 3;      nloc = bx;     }
    const int n0 = nloc * 128;
    const u16* Bt = Wb + (size_t)widx * (D_ * D_);
    const float* bias = (MODE == 0) ? (widx == 0 ? b0 : widx == 1 ? b1 : b2) : b0;

    // staging coords: thread t covers row t/4 (and +64), 16B chunk (t&3)
    const int srow  = t >> 2;
    const int sbyte = (t & 3) * 16;
    const char* Ag = (const char*)(A  + (size_t)(m0 + srow) * D_) + sbyte;
    const char* Bg = (const char*)(Bt + (size_t)(n0 + srow) * D_) + sbyte;
    char* Al = (char*)Als + w * 1024;   // wave-uniform LDS dest base
    char* Bl = (char*)Bls + w * 1024;

    f32x4 acc[4][4];
#pragma unroll
    for (int i = 0; i < 4; i++)
#pragma unroll
        for (int j = 0; j < 4; j++) acc[i][j] = (f32x4){0.f, 0.f, 0.f, 0.f};

    const int mbase = (w >> 1) * 64, nbase = (w & 1) * 64;
    const int fr   = l & 15;           // fragment row/col within 16
    const int koff = (l >> 4) * 8;     // k-group offset (elems)

    for (int kt = 0; kt < D_; kt += 32) {
        const int cb = kt * 2;         // BYTE offset along K
        gload_lds16(Ag + cb,                 Al);
        gload_lds16(Ag + cb + 64 * (D_ * 2), Al + 4096);
        gload_lds16(Bg + cb,                 Bl);
        gload_lds16(Bg + cb + 64 * (D_ * 2), Bl + 4096);
        __syncthreads();

        bf16x8 af[4], bf[4];
#pragma unroll
        for (int mi = 0; mi < 4; mi++)
            af[mi] = *(const bf16x8*)(Als + (mbase + mi * 16 + fr) * 32 + koff);
#pragma unroll
        for (int ni = 0; ni < 4; ni++)
            bf[ni] = *(const bf16x8*)(Bls + (nbase + ni * 16 + fr) * 32 + koff);
#pragma unroll
        for (int mi = 0; mi < 4; mi++)
#pragma unroll
            for (int ni = 0; ni < 4; ni++)
                acc[mi][ni] = __builtin_amdgcn_mfma_f32_16x16x32_bf16(
                    af[mi], bf[ni], acc[mi][ni], 0, 0, 0);
        __syncthreads();
    }

    // epilogue: C[row=(l>>4)*4+r + mi*16 + mbase][col=fr + ni*16 + nbase]
    const int crow0 = m0 + mbase + (l >> 4) * 4;
    const int ccol0 = nbase + fr;
    if (MODE == 0) {
        const int cbase = widx * D_ + n0;
#pragma unroll
        for (int mi = 0; mi < 4; mi++)
#pragma unroll
            for (int ni = 0; ni < 4; ni++) {
                const int cc = ccol0 + ni * 16;
                const float bv = bias[n0 + cc];
#pragma unroll
                for (int r = 0; r < 4; r++)
                    outb[(size_t)(crow0 + mi * 16 + r) * NQKV_ + cbase + cc] =
                        f2bf(acc[mi][ni][r] + bv);
            }
    } else {
#pragma unroll
        for (int mi = 0; mi < 4; mi++)
#pragma unroll
            for (int ni = 0; ni < 4; ni++) {
                const int cc = n0 + ccol0 + ni * 16;
                const float bv = bias[cc];
#pragma unroll
                for (int r = 0; r < 4; r++) {
                    const size_t idx = (size_t)(crow0 + mi * 16 + r) * D_ + cc;
                    outf[idx] = acc[mi][ni][r] + bv + xres[idx];
                }
            }
    }
}

// ---------------- local attention: one wave per (m, head-quad) ----------------
// lane l: head (l>>4) of the quad, elements 4*(l&15)..+3 as u16x4.
// Dot reduce = 4 shuffle steps within 16-lane groups (serves 4 heads at once).
__global__ __launch_bounds__(256) void attn_kernel(const u16* __restrict__ QKV,
                                                   const float* __restrict__ bk,
                                                   const float* __restrict__ bv,
                                                   u16* __restrict__ att) {
    const int gw = xcd_swz(blockIdx.x, gridDim.x) * 4 + (threadIdx.x >> 6);
    const int l  = threadIdx.x & 63;
    const int hq = gw % 3;             // head-quad index (heads 4hq..4hq+3)
    const int m  = gw / 3;
    const int s  = m & (S_ - 1);
    const int col = hq * 256 + l * 4;  // element column in [0,768)
    const u16* base = QKV + (size_t)m * NQKV_;

    const u16x4 qv = *(const u16x4*)(base + col);
    float qf[4];
#pragma unroll
    for (int j = 0; j < 4; j++) qf[j] = bf2f(qv[j]);

    float sc[5];
#pragma unroll
    for (int i = 0; i < 5; i++) {
        const int sp = s + i - 2;
        float p;
        if (sp >= 0 && sp < S_) {
            const u16x4 kv = *(const u16x4*)(base + (i - 2) * NQKV_ + D_ + col);
            p = qf[0] * bf2f(kv[0]) + qf[1] * bf2f(kv[1])
              + qf[2] * bf2f(kv[2]) + qf[3] * bf2f(kv[3]);
        } else {
            const float4 kb = *(const float4*)(bk + col);
            p = qf[0] * kb.x + qf[1] * kb.y + qf[2] * kb.z + qf[3] * kb.w;
        }
#pragma unroll
        for (int off = 1; off < 16; off <<= 1) p += __shfl_xor(p, off, 64);
        sc[i] = p * 0.125f;            // / sqrt(64)
    }
    float mx = sc[0];
#pragma unroll
    for (int i = 1; i < 5; i++) mx = fmaxf(mx, sc[i]);
    float e[5], sum = 0.f;
#pragma unroll
    for (int i = 0; i < 5; i++) { e[i] = __expf(sc[i] - mx); sum += e[i]; }
    const float inv = 1.f / sum;

    float o[4] = {0.f, 0.f, 0.f, 0.f};
#pragma unroll
    for (int i = 0; i < 5; i++) {
        const float wgt = e[i] * inv;
        const int sp = s + i - 2;
        if (sp >= 0 && sp < S_) {
            const u16x4 vv = *(const u16x4*)(base + (i - 2) * NQKV_ + 2 * D_ + col);
#pragma unroll
            for (int j = 0; j < 4; j++) o[j] += wgt * bf2f(vv[j]);
        } else {
            const float4 vb = *(const float4*)(bv + col);
            o[0] += wgt * vb.x; o[1] += wgt * vb.y;
            o[2] += wgt * vb.z; o[3] += wgt * vb.w;
        }
    }
    u16x4 ov;
#pragma unroll
    for (int j = 0; j < 4; j++) ov[j] = f2bf(o[j]);
    *(u16x4*)(att + (size_t)m * D_ + col) = ov;
}

// ---------------- LayerNorm over rows of 768 ----------------
__global__ __launch_bounds__(256) void ln_kernel(const float* __restrict__ Y,
                                                 const float* __restrict__ gamma,
                                                 const float* __restrict__ beta,
                                                 float* __restrict__ out) {
    const int row = blockIdx.x;
    const float* r = Y + (size_t)row * D_;
    const int t = threadIdx.x;
    const float v0 = r[t], v1 = r[t + 256], v2 = r[t + 512];
    float s  = v0 + v1 + v2;
    float s2 = v0 * v0 + v1 * v1 + v2 * v2;
#pragma unroll
    for (int off = 32; off > 0; off >>= 1) {
        s  += __shfl_xor(s,  off, 64);
        s2 += __shfl_xor(s2, off, 64);
    }
    __shared__ float red[8];
    const int w = t >> 6, l = t & 63;
    if (l == 0) { red[w] = s; red[4 + w] = s2; }
    __syncthreads();
    s  = red[0] + red[1] + red[2] + red[3];
    s2 = red[4] + red[5] + red[6] + red[7];
    const float mu  = s * (1.f / 768.f);
    const float var = s2 * (1.f / 768.f) - mu * mu;
    const float inv = rsqrtf(var + 1e-5f);
    float* o = out + (size_t)row * D_;
    o[t]       = (v0 - mu) * inv * gamma[t]       + beta[t];
    o[t + 256] = (v1 - mu) * inv * gamma[t + 256] + beta[t + 256];
    o[t + 512] = (v2 - mu) * inv * gamma[t + 512] + beta[t + 512];
}

extern "C" void kernel_launch(void* const* d_in, const int* in_sizes, int n_in,
                              void* d_out, int out_size, void* d_ws, size_t ws_size,
                              hipStream_t stream) {
    const float* x     = (const float*)d_in[0];
    const float* Wq    = (const float*)d_in[1];
    const float* bq    = (const float*)d_in[2];
    const float* Wk    = (const float*)d_in[3];
    const float* bk    = (const float*)d_in[4];
    const float* Wv    = (const float*)d_in[5];
    const float* bv    = (const float*)d_in[6];
    const float* Wo    = (const float*)d_in[7];
    const float* bo    = (const float*)d_in[8];
    const float* gamma = (const float*)d_in[9];
    const float* beta  = (const float*)d_in[10];

    char* ws = (char*)d_ws;
    // layout: Wb (4x768x768 bf16) | xb/att (M*768 bf16) | QKV (M*2304 bf16, reused as y' f32)
    u16*   Wb  = (u16*)ws;                                  //  4,718,592 B
    u16*   xb  = (u16*)(ws + 4718592);                      // 50,331,648 B
    u16*   QKV = (u16*)(ws + 4718592 + 50331648);           // 150,994,944 B
    float* yp  = (float*)QKV;                               // reuse (100 MB <= 151 MB)
    u16*   att = xb;                                        // reuse after QKV GEMM

    castx_kernel<<<(M_ * D_) / (256 * 4), 256, 0, stream>>>(x, xb);
    wtrans_kernel<<<dim3(24, 24, 4), 256, 0, stream>>>(Wq, Wk, Wv, Wo, Wb);
    gemm_kernel<0><<<18 * (M_ / 128), 256, 0, stream>>>(xb, Wb, bq, bk, bv,
                                                        QKV, nullptr, nullptr);
    attn_kernel<<<(M_ * 3) / 4, 256, 0, stream>>>(QKV, bk, bv, att);
    gemm_kernel<1><<<6 * (M_ / 128), 256, 0, stream>>>(att, Wb, bo, nullptr, nullptr,
                                                       nullptr, yp, x);
    ln_kernel<<<M_, 256, 0, stream>>>(yp, gamma, beta, (float*)d_out);
}

// Round 4
// 354.065 us; speedup vs baseline: 1.4399x; 1.0032x over previous
//
#include <hip/hip_runtime.h>

#define B_  8
#define S_  4096
#define D_  768
#define H_  12
#define M_  (B_ * S_)      // 32768
#define NQKV_ 2304         // 3*D
#define NTILES 12          // 768 / 64

typedef unsigned short u16;
typedef __attribute__((ext_vector_type(4))) float  f32x4;
typedef __attribute__((ext_vector_type(8))) __bf16 bf16x8;
typedef __attribute__((ext_vector_type(4))) u16    u16x4;

#define GAS __attribute__((address_space(1)))
#define LAS __attribute__((address_space(3)))

__device__ __forceinline__ u16 f2bf(float f) {
    unsigned u = __float_as_uint(f);
    u += 0x7FFF + ((u >> 16) & 1);          // round-to-nearest-even
    return (u16)(u >> 16);
}
__device__ __forceinline__ float bf2f(u16 h) {
    return __uint_as_float(((unsigned)h) << 16);
}

__device__ __forceinline__ void gload_lds16(const void* g, void* l) {
    __builtin_amdgcn_global_load_lds((const GAS void*)g, (LAS void*)l, 16, 0, 0);
}

// bijective XCD swizzle (nwg % 8 == 0): each XCD gets a contiguous work chunk
__device__ __forceinline__ int xcd_swz(int bid, int nwg) {
    return (bid & 7) * (nwg >> 3) + (bid >> 3);
}

// ---------------- cast x (f32 -> bf16) ----------------
__global__ __launch_bounds__(256) void castx_kernel(const float* __restrict__ x,
                                                    u16* __restrict__ xb) {
    const int i = blockIdx.x * 256 + threadIdx.x;
    const float4 v = ((const float4*)x)[i];
    u16x4 o;
    o.x = f2bf(v.x); o.y = f2bf(v.y); o.z = f2bf(v.z); o.w = f2bf(v.w);
    ((u16x4*)xb)[i] = o;
}

// ---------------- weight transpose+cast: W[k][n] f32 -> Wb[n][k] bf16 ----------------
__global__ __launch_bounds__(256) void wtrans_kernel(const float* __restrict__ Wq,
                                                     const float* __restrict__ Wk,
                                                     const float* __restrict__ Wv,
                                                     const float* __restrict__ Wo,
                                                     u16* __restrict__ Wb) {
    const float* W = (blockIdx.z == 0) ? Wq : (blockIdx.z == 1) ? Wk
                   : (blockIdx.z == 2) ? Wv : Wo;
    u16* O = Wb + (size_t)blockIdx.z * D_ * D_;
    __shared__ float tile[32][33];
    const int tx = threadIdx.x & 31, ty = threadIdx.x >> 5;  // 32x8
    const int k0 = blockIdx.y * 32, n0 = blockIdx.x * 32;
#pragma unroll
    for (int j = 0; j < 4; j++)
        tile[ty + j * 8][tx] = W[(size_t)(k0 + ty + j * 8) * D_ + n0 + tx];
    __syncthreads();
#pragma unroll
    for (int j = 0; j < 4; j++)
        O[(size_t)(n0 + ty + j * 8) * D_ + k0 + tx] = f2bf(tile[tx][ty + j * 8]);
}

// ============ 256x256 8-phase bf16 MFMA GEMM (T2+T3+T4+T5) ============
// A [M][768] bf16 row-major; Bt = weight [n][k] bf16.
// 512 threads = 8 waves (2M x 4N), per-wave C = 128x64, BK=64, 12 K-tiles.
// LDS 128 KiB: 2 buffers x (A 256x64 + B 256x64) bf16.
// Swizzle: 16B-chunk c within a 128B row stored at c ^ (row&7)
//   (pre-swizzled global source for global_load_lds; swizzled ds_read).
// MODE 0: QKV (out bf16 [M][2304], +bias)
// MODE 1: OUT (out bf16 y' [M][768], + bo + bf16 residual)

#define SYNC_NOVM()                                          \
    __builtin_amdgcn_sched_barrier(0);                       \
    __builtin_amdgcn_s_barrier();                            \
    asm volatile("s_waitcnt lgkmcnt(0)" ::: "memory");       \
    __builtin_amdgcn_sched_barrier(0)

#define SYNC_VM(N)                                           \
    __builtin_amdgcn_sched_barrier(0);                       \
    asm volatile("s_waitcnt vmcnt(" #N ")" ::: "memory");    \
    __builtin_amdgcn_s_barrier();                            \
    asm volatile("s_waitcnt lgkmcnt(0)" ::: "memory");       \
    __builtin_amdgcn_sched_barrier(0)

#define TRAIL()                                              \
    __builtin_amdgcn_sched_barrier(0);                       \
    __builtin_amdgcn_s_barrier()

#define MFMA_Q(AF, BF, MO, NO)                                               \
    __builtin_amdgcn_s_setprio(1);                                           \
    _Pragma("unroll") for (int mi = 0; mi < 4; ++mi)                         \
        _Pragma("unroll") for (int ni = 0; ni < 2; ++ni)                     \
            _Pragma("unroll") for (int kh = 0; kh < 2; ++kh)                 \
                acc[mi + MO][ni + NO] =                                      \
                    __builtin_amdgcn_mfma_f32_16x16x32_bf16(                 \
                        AF[mi][kh], BF[ni][kh], acc[mi + MO][ni + NO], 0, 0, 0); \
    __builtin_amdgcn_s_setprio(0)

template <int MODE>
__global__ __launch_bounds__(512, 2) void gemm8_kernel(
    const u16* __restrict__ A, const u16* __restrict__ Wb,
    const float* __restrict__ b0, const float* __restrict__ b1,
    const float* __restrict__ b2,
    u16* __restrict__ outb, const u16* __restrict__ xres) {
    extern __shared__ char lds[];

    const int t = threadIdx.x;
    const int w = t >> 6, l = t & 63;
    const int wm = w >> 2, wn = w & 3;

    const int NTN = (MODE == 0) ? 9 : 3;
    const int work = xcd_swz(blockIdx.x, gridDim.x);
    const int mt = work / NTN, nt = work % NTN;
    const int m0 = mt * 256;
    const int n0 = nt * 256;
    const int widx = (MODE == 0) ? (n0 / D_) : 3;
    const int n0w = n0 - ((MODE == 0) ? widx * D_ : 0);   // col base within weight

    // ---- staging addresses (pre-swizzled global source) ----
    const int srow   = t >> 3;                       // 0..63
    const int schunk = (t & 7) ^ (srow & 7);         // swizzled 16B chunk 0..7
    const u16* Asrc = A + (size_t)(m0 + srow) * D_ + schunk * 8;
    const u16* Bsrc = Wb + (size_t)widx * (D_ * D_) + (size_t)(n0w + srow) * D_ + schunk * 8;

    // half-tile stage: 128 rows x 64 cols = 2 x global_load_lds(16B)
    auto STAGE_A = [&](int h, int tk, int db) {
        const u16* s = Asrc + (size_t)(h * 128) * D_ + tk * 64;
        char* d = lds + db * 65536 + h * 16384 + (w << 10);
        gload_lds16(s, d);
        gload_lds16(s + 64 * D_, d + 8192);
    };
    auto STAGE_B = [&](int h, int tk, int db) {
        const u16* s = Bsrc + (size_t)(h * 128) * D_ + tk * 64;
        char* d = lds + db * 65536 + 32768 + h * 16384 + (w << 10);
        gload_lds16(s, d);
        gload_lds16(s + 64 * D_, d + 8192);
    };

    // ---- fragment read addressing (swizzled) ----
    const int ck0 = (((l >> 4) ^ (l & 7)) << 4);
    const int ck1 = ((((l >> 4) + 4) ^ (l & 7)) << 4);
    const int aRowB = (wm * 128 + (l & 15)) * 128;            // byte in A region
    const int bRowB = 32768 + (wn * 64 + (l & 15)) * 128;     // byte in B region
#define LDSREAD(off) (*(const bf16x8*)(lds + (off)))

    f32x4 acc[8][4];
#pragma unroll
    for (int i = 0; i < 8; i++)
#pragma unroll
        for (int j = 0; j < 4; j++) acc[i][j] = (f32x4){0.f, 0.f, 0.f, 0.f};

    bf16x8 Alo[4][2], Ahi[4][2], Ba[2][2], Bb[2][2];

    // ---- prologue: stage tile0 (buf0) + A/B... of tile1 (buf1) ----
    STAGE_A(0, 0, 0); STAGE_A(1, 0, 0); STAGE_B(0, 0, 0); STAGE_B(1, 0, 0);
    STAGE_A(0, 1, 1); STAGE_A(1, 1, 1); STAGE_B(0, 1, 1);
    __builtin_amdgcn_sched_barrier(0);
    asm volatile("s_waitcnt vmcnt(6)" ::: "memory");   // tile0 fully landed
    __builtin_amdgcn_s_barrier();
    // preload regs for tile 0
#pragma unroll
    for (int mi = 0; mi < 4; ++mi) {
        Alo[mi][0] = LDSREAD(aRowB + mi * 2048 + ck0);
        Alo[mi][1] = LDSREAD(aRowB + mi * 2048 + ck1);
    }
#pragma unroll
    for (int ni = 0; ni < 2; ++ni) {
        Ba[ni][0] = LDSREAD(bRowB + ni * 2048 + ck0);
        Ba[ni][1] = LDSREAD(bRowB + ni * 2048 + ck1);
    }

    for (int X = 0; X < NTILES; ++X) {
        const int bX = X & 1;
        const int L0off = bX << 16;
        const int L1off = (bX ^ 1) << 16;
        int t1 = X + 1; if (t1 >= NTILES) t1 -= NTILES;   // wrap keeps vmcnt counts uniform
        int t2 = X + 2; if (t2 >= NTILES) t2 -= NTILES;

        // ---- phase 1: q(0,0); read A_hi[X], B_b[X]; stage B-bot[X+1] ----
#pragma unroll
        for (int mi = 0; mi < 4; ++mi) {
            Ahi[mi][0] = LDSREAD(L0off + aRowB + (mi + 4) * 2048 + ck0);
            Ahi[mi][1] = LDSREAD(L0off + aRowB + (mi + 4) * 2048 + ck1);
        }
#pragma unroll
        for (int ni = 0; ni < 2; ++ni) {
            Bb[ni][0] = LDSREAD(L0off + bRowB + (ni + 2) * 2048 + ck0);
            Bb[ni][1] = LDSREAD(L0off + bRowB + (ni + 2) * 2048 + ck1);
        }
        STAGE_B(1, t1, bX ^ 1);
        SYNC_NOVM();
        MFMA_Q(Alo, Ba, 0, 0);
        TRAIL();

        // ---- phase 2: q(0,1); stage A-top[X+2] ----
        STAGE_A(0, t2, bX);
        SYNC_VM(6);
        MFMA_Q(Alo, Bb, 0, 2);
        TRAIL();

        // ---- phase 3: q(1,0); read A_lo[X+1]; stage A-bot[X+2] ----
#pragma unroll
        for (int mi = 0; mi < 4; ++mi) {
            Alo[mi][0] = LDSREAD(L1off + aRowB + mi * 2048 + ck0);
            Alo[mi][1] = LDSREAD(L1off + aRowB + mi * 2048 + ck1);
        }
        STAGE_A(1, t2, bX);
        SYNC_VM(4);
        MFMA_Q(Ahi, Ba, 4, 0);
        TRAIL();

        // ---- phase 4: q(1,1); read B_a[X+1]; stage B-top[X+2] ----
#pragma unroll
        for (int ni = 0; ni < 2; ++ni) {
            Ba[ni][0] = LDSREAD(L1off + bRowB + ni * 2048 + ck0);
            Ba[ni][1] = LDSREAD(L1off + bRowB + ni * 2048 + ck1);
        }
        STAGE_B(0, t2, bX);
        SYNC_VM(6);
        MFMA_Q(Ahi, Bb, 4, 2);
        TRAIL();
    }

    // ---- epilogue ----
    const int crow0 = m0 + wm * 128 + ((l >> 4) << 2);
    const int ccol0 = n0 + wn * 64 + (l & 15);
    if (MODE == 0) {
        const float* bias = (widx == 0) ? b0 : (widx == 1) ? b1 : b2;
        const int bcol0 = ccol0 - widx * D_;
#pragma unroll
        for (int mi = 0; mi < 8; ++mi)
#pragma unroll
            for (int ni = 0; ni < 4; ++ni) {
                const float bv = bias[bcol0 + ni * 16];
#pragma unroll
                for (int r = 0; r < 4; ++r)
                    outb[(size_t)(crow0 + mi * 16 + r) * NQKV_ + ccol0 + ni * 16] =
                        f2bf(acc[mi][ni][r] + bv);
            }
    } else {
#pragma unroll
        for (int mi = 0; mi < 8; ++mi)
#pragma unroll
            for (int ni = 0; ni < 4; ++ni) {
                const int col = ccol0 + ni * 16;
                const float bv = b0[col];
#pragma unroll
                for (int r = 0; r < 4; ++r) {
                    const size_t idx = (size_t)(crow0 + mi * 16 + r) * D_ + col;
                    outb[idx] = f2bf(acc[mi][ni][r] + bv + bf2f(xres[idx]));
                }
            }
    }
}

// ---------------- local attention: one wave per (m, head-quad) ----------------
__global__ __launch_bounds__(256) void attn_kernel(const u16* __restrict__ QKV,
                                                   const float* __restrict__ bk,
                                                   const float* __restrict__ bv,
                                                   u16* __restrict__ att) {
    const int gw = xcd_swz(blockIdx.x, gridDim.x) * 4 + (threadIdx.x >> 6);
    const int l  = threadIdx.x & 63;
    const int hq = gw % 3;             // head-quad index
    const int m  = gw / 3;
    const int s  = m & (S_ - 1);
    const int col = hq * 256 + l * 4;
    const u16* base = QKV + (size_t)m * NQKV_;

    const u16x4 qv = *(const u16x4*)(base + col);
    float qf[4];
#pragma unroll
    for (int j = 0; j < 4; j++) qf[j] = bf2f(qv[j]);

    float sc[5];
#pragma unroll
    for (int i = 0; i < 5; i++) {
        const int sp = s + i - 2;
        float p;
        if (sp >= 0 && sp < S_) {
            const u16x4 kv = *(const u16x4*)(base + (i - 2) * NQKV_ + D_ + col);
            p = qf[0] * bf2f(kv[0]) + qf[1] * bf2f(kv[1])
              + qf[2] * bf2f(kv[2]) + qf[3] * bf2f(kv[3]);
        } else {
            const float4 kb = *(const float4*)(bk + col);
            p = qf[0] * kb.x + qf[1] * kb.y + qf[2] * kb.z + qf[3] * kb.w;
        }
#pragma unroll
        for (int off = 1; off < 16; off <<= 1) p += __shfl_xor(p, off, 64);
        sc[i] = p * 0.125f;
    }
    float mx = sc[0];
#pragma unroll
    for (int i = 1; i < 5; i++) mx = fmaxf(mx, sc[i]);
    float e[5], sum = 0.f;
#pragma unroll
    for (int i = 0; i < 5; i++) { e[i] = __expf(sc[i] - mx); sum += e[i]; }
    const float inv = 1.f / sum;

    float o[4] = {0.f, 0.f, 0.f, 0.f};
#pragma unroll
    for (int i = 0; i < 5; i++) {
        const float wgt = e[i] * inv;
        const int sp = s + i - 2;
        if (sp >= 0 && sp < S_) {
            const u16x4 vv = *(const u16x4*)(base + (i - 2) * NQKV_ + 2 * D_ + col);
#pragma unroll
            for (int j = 0; j < 4; j++) o[j] += wgt * bf2f(vv[j]);
        } else {
            const float4 vb = *(const float4*)(bv + col);
            o[0] += wgt * vb.x; o[1] += wgt * vb.y;
            o[2] += wgt * vb.z; o[3] += wgt * vb.w;
        }
    }
    u16x4 ov;
#pragma unroll
    for (int j = 0; j < 4; j++) ov[j] = f2bf(o[j]);
    *(u16x4*)(att + (size_t)m * D_ + col) = ov;
}

// ---------------- LayerNorm over rows of 768 (bf16 in, f32 out) ----------------
__global__ __launch_bounds__(256) void ln_kernel(const u16* __restrict__ Yb,
                                                 const float* __restrict__ gamma,
                                                 const float* __restrict__ beta,
                                                 float* __restrict__ out) {
    const int row = blockIdx.x;
    const u16* r = Yb + (size_t)row * D_;
    const int t = threadIdx.x;
    const float v0 = bf2f(r[t]), v1 = bf2f(r[t + 256]), v2 = bf2f(r[t + 512]);
    float s  = v0 + v1 + v2;
    float s2 = v0 * v0 + v1 * v1 + v2 * v2;
#pragma unroll
    for (int off = 32; off > 0; off >>= 1) {
        s  += __shfl_xor(s,  off, 64);
        s2 += __shfl_xor(s2, off, 64);
    }
    __shared__ float red[8];
    const int w = t >> 6, l = t & 63;
    if (l == 0) { red[w] = s; red[4 + w] = s2; }
    __syncthreads();
    s  = red[0] + red[1] + red[2] + red[3];
    s2 = red[4] + red[5] + red[6] + red[7];
    const float mu  = s * (1.f / 768.f);
    const float var = s2 * (1.f / 768.f) - mu * mu;
    const float inv = rsqrtf(var + 1e-5f);
    float* o = out + (size_t)row * D_;
    o[t]       = (v0 - mu) * inv * gamma[t]       + beta[t];
    o[t + 256] = (v1 - mu) * inv * gamma[t + 256] + beta[t + 256];
    o[t + 512] = (v2 - mu) * inv * gamma[t + 512] + beta[t + 512];
}

extern "C" void kernel_launch(void* const* d_in, const int* in_sizes, int n_in,
                              void* d_out, int out_size, void* d_ws, size_t ws_size,
                              hipStream_t stream) {
    const float* x     = (const float*)d_in[0];
    const float* Wq    = (const float*)d_in[1];
    const float* bq    = (const float*)d_in[2];
    const float* Wk    = (const float*)d_in[3];
    const float* bk    = (const float*)d_in[4];
    const float* Wv    = (const float*)d_in[5];
    const float* bv    = (const float*)d_in[6];
    const float* Wo    = (const float*)d_in[7];
    const float* bo    = (const float*)d_in[8];
    const float* gamma = (const float*)d_in[9];
    const float* beta  = (const float*)d_in[10];

    char* ws = (char*)d_ws;
    u16*   Wb  = (u16*)ws;                                  //  4,718,592 B
    u16*   xb  = (u16*)(ws + 4718592);                      // 50,331,648 B (stays live)
    u16*   QKV = (u16*)(ws + 4718592 + 50331648);           // 150,994,944 B
    u16*   yb  = QKV;                                       // reuse after attn
    u16*   att = (u16*)d_out;                               // scratch in d_out (50 MB of 100)

    (void)hipFuncSetAttribute(reinterpret_cast<const void*>(&gemm8_kernel<0>),
                              hipFuncAttributeMaxDynamicSharedMemorySize, 131072);
    (void)hipFuncSetAttribute(reinterpret_cast<const void*>(&gemm8_kernel<1>),
                              hipFuncAttributeMaxDynamicSharedMemorySize, 131072);

    castx_kernel<<<(M_ * D_) / (256 * 4), 256, 0, stream>>>(x, xb);
    wtrans_kernel<<<dim3(24, 24, 4), 256, 0, stream>>>(Wq, Wk, Wv, Wo, Wb);
    gemm8_kernel<0><<<(M_ / 256) * 9, 512, 131072, stream>>>(xb, Wb, bq, bk, bv,
                                                             QKV, nullptr);
    attn_kernel<<<(M_ * 3) / 4, 256, 0, stream>>>(QKV, bk, bv, att);
    gemm8_kernel<1><<<(M_ / 256) * 3, 512, 131072, stream>>>(att, Wb, bo, nullptr, nullptr,
                                                             yb, xb);
    ln_kernel<<<M_, 256, 0, stream>>>(yb, gamma, beta, (float*)d_out);
}

// Round 5
// 329.860 us; speedup vs baseline: 1.5455x; 1.0734x over previous
//
#include <hip/hip_runtime.h>

#define B_  8
#define S_  4096
#define D_  768
#define H_  12
#define M_  (B_ * S_)      // 32768
#define NQKV_ 2304         // 3*D
#define NTILES 12          // 768 / 64

typedef unsigned short u16;
typedef __attribute__((ext_vector_type(4))) float  f32x4;
typedef __attribute__((ext_vector_type(8))) __bf16 bf16x8;
typedef __attribute__((ext_vector_type(4))) u16    u16x4;

#define GAS __attribute__((address_space(1)))
#define LAS __attribute__((address_space(3)))

__device__ __forceinline__ u16 f2bf(float f) {
    unsigned u = __float_as_uint(f);
    u += 0x7FFF + ((u >> 16) & 1);          // round-to-nearest-even
    return (u16)(u >> 16);
}
__device__ __forceinline__ float bf2f(u16 h) {
    return __uint_as_float(((unsigned)h) << 16);
}

__device__ __forceinline__ void gload_lds16(const void* g, void* l) {
    __builtin_amdgcn_global_load_lds((const GAS void*)g, (LAS void*)l, 16, 0, 0);
}

// bijective XCD swizzle (nwg % 8 == 0): each XCD gets a contiguous work chunk
__device__ __forceinline__ int xcd_swz(int bid, int nwg) {
    return (bid & 7) * (nwg >> 3) + (bid >> 3);
}

// ---------------- cast x (f32 -> bf16) ----------------
__global__ __launch_bounds__(256) void castx_kernel(const float* __restrict__ x,
                                                    u16* __restrict__ xb) {
    const int i = blockIdx.x * 256 + threadIdx.x;
    const float4 v = ((const float4*)x)[i];
    u16x4 o;
    o.x = f2bf(v.x); o.y = f2bf(v.y); o.z = f2bf(v.z); o.w = f2bf(v.w);
    ((u16x4*)xb)[i] = o;
}

// ---------------- weight transpose+cast: W[k][n] f32 -> Wb[n][k] bf16 ----------------
__global__ __launch_bounds__(256) void wtrans_kernel(const float* __restrict__ Wq,
                                                     const float* __restrict__ Wk,
                                                     const float* __restrict__ Wv,
                                                     const float* __restrict__ Wo,
                                                     u16* __restrict__ Wb) {
    const float* W = (blockIdx.z == 0) ? Wq : (blockIdx.z == 1) ? Wk
                   : (blockIdx.z == 2) ? Wv : Wo;
    u16* O = Wb + (size_t)blockIdx.z * D_ * D_;
    __shared__ float tile[32][33];
    const int tx = threadIdx.x & 31, ty = threadIdx.x >> 5;  // 32x8
    const int k0 = blockIdx.y * 32, n0 = blockIdx.x * 32;
#pragma unroll
    for (int j = 0; j < 4; j++)
        tile[ty + j * 8][tx] = W[(size_t)(k0 + ty + j * 8) * D_ + n0 + tx];
    __syncthreads();
#pragma unroll
    for (int j = 0; j < 4; j++)
        O[(size_t)(n0 + ty + j * 8) * D_ + k0 + tx] = f2bf(tile[tx][ty + j * 8]);
}

// ============ 256x256 pipelined bf16 MFMA GEMM ============
// 512 threads = 8 waves (2M x 4N), per-wave C = 128x64, BK=64, 12 K-tiles.
// LDS 128 KiB = 2 buffers x (A 256x64 + B 256x64) bf16, XOR-swizzled.
// Register loads pipelined ONE PHASE AHEAD of their MFMA consumer; no asm
// lgkmcnt (compiler inserts counted waits); counted vmcnt at phase ends only.
// Phase map (per K-tile X):
//  P1: read Bb[X]+Ahi[X];  stage B0[X+1]->buf^1; MFMA Alo*Ba; vmcnt(8)
//  P2: (no reads)          stage B1[X+2]->buf;   MFMA Alo*Bb; vmcnt(4)
//  P3: read Alo[X+1];      stage A0[X+2]->buf;   MFMA Ahi*Ba; vmcnt(4)
//  P4: read Ba[X+1];       stage A1[X+2]->buf;   MFMA Ahi*Bb; vmcnt(8)

#define PHASE_END(N)                                         \
    __builtin_amdgcn_sched_barrier(0);                       \
    asm volatile("s_waitcnt vmcnt(" #N ")" ::: "memory");    \
    __builtin_amdgcn_s_barrier();                            \
    __builtin_amdgcn_sched_barrier(0)

#define MFMA_Q(AF, BF, MO, NO)                                               \
    _Pragma("unroll") for (int mi = 0; mi < 4; ++mi)                         \
        _Pragma("unroll") for (int ni = 0; ni < 2; ++ni)                     \
            _Pragma("unroll") for (int kh = 0; kh < 2; ++kh)                 \
                acc[mi + MO][ni + NO] =                                      \
                    __builtin_amdgcn_mfma_f32_16x16x32_bf16(                 \
                        AF[mi][kh], BF[ni][kh], acc[mi + MO][ni + NO], 0, 0, 0)

template <int MODE>
__global__ __launch_bounds__(512, 2) void gemm8_kernel(
    const u16* __restrict__ A, const u16* __restrict__ Wb,
    const float* __restrict__ b0, const float* __restrict__ b1,
    const float* __restrict__ b2,
    u16* __restrict__ outb, const u16* __restrict__ xres) {
    extern __shared__ char lds[];

    const int t = threadIdx.x;
    const int w = t >> 6, l = t & 63;
    const int wm = w >> 2, wn = w & 3;

    const int NTN = (MODE == 0) ? 9 : 3;
    const int work = xcd_swz(blockIdx.x, gridDim.x);
    const int mt = work / NTN, nt = work % NTN;
    const int m0 = mt * 256;
    const int n0 = nt * 256;
    const int widx = (MODE == 0) ? (n0 / D_) : 3;
    const int n0w = n0 - ((MODE == 0) ? widx * D_ : 0);   // col base within weight

    // ---- staging addresses (pre-swizzled global source) ----
    const int srow   = t >> 3;                       // 0..63
    const int schunk = (t & 7) ^ (srow & 7);         // swizzled 16B chunk 0..7
    const u16* Asrc = A + (size_t)(m0 + srow) * D_ + schunk * 8;
    const u16* Bsrc = Wb + (size_t)widx * (D_ * D_) + (size_t)(n0w + srow) * D_ + schunk * 8;

    // half-tile stage: 128 rows x 64 cols = 2 x global_load_lds(16B) per wave
    auto STAGE_A = [&](int h, int tk, int db) {
        const u16* s = Asrc + (size_t)(h * 128) * D_ + tk * 64;
        char* d = lds + db * 65536 + h * 16384 + (w << 10);
        gload_lds16(s, d);
        gload_lds16(s + 64 * D_, d + 8192);
    };
    auto STAGE_B = [&](int h, int tk, int db) {
        const u16* s = Bsrc + (size_t)(h * 128) * D_ + tk * 64;
        char* d = lds + db * 65536 + 32768 + h * 16384 + (w << 10);
        gload_lds16(s, d);
        gload_lds16(s + 64 * D_, d + 8192);
    };

    // ---- fragment read addressing (swizzled) ----
    const int ck0 = (((l >> 4) ^ (l & 7)) << 4);
    const int ck1 = ((((l >> 4) + 4) ^ (l & 7)) << 4);
    const int aRowB = (wm * 128 + (l & 15)) * 128;            // byte in A region
    const int bRowB = 32768 + (wn * 64 + (l & 15)) * 128;     // byte in B region
#define LDSREAD(off) (*(const bf16x8*)(lds + (off)))

    f32x4 acc[8][4];
#pragma unroll
    for (int i = 0; i < 8; i++)
#pragma unroll
        for (int j = 0; j < 4; j++) acc[i][j] = (f32x4){0.f, 0.f, 0.f, 0.f};

    bf16x8 Alo[4][2], Ahi[4][2], Ba[2][2], Bb[2][2];

    // ---- prologue: tile0 (8 loads) then B1[1],A0[1],A1[1] (6 loads) ----
    STAGE_A(0, 0, 0); STAGE_A(1, 0, 0); STAGE_B(0, 0, 0); STAGE_B(1, 0, 0);
    STAGE_B(1, 1, 1); STAGE_A(0, 1, 1); STAGE_A(1, 1, 1);
    __builtin_amdgcn_sched_barrier(0);
    asm volatile("s_waitcnt vmcnt(6)" ::: "memory");   // tile0 fully landed
    __builtin_amdgcn_s_barrier();
    __builtin_amdgcn_sched_barrier(0);
    // preload regs for tile 0 (buf0)
#pragma unroll
    for (int mi = 0; mi < 4; ++mi) {
        Alo[mi][0] = LDSREAD(aRowB + mi * 2048 + ck0);
        Alo[mi][1] = LDSREAD(aRowB + mi * 2048 + ck1);
    }
#pragma unroll
    for (int ni = 0; ni < 2; ++ni) {
        Ba[ni][0] = LDSREAD(bRowB + ni * 2048 + ck0);
        Ba[ni][1] = LDSREAD(bRowB + ni * 2048 + ck1);
    }

    for (int X = 0; X < NTILES; ++X) {
        const int bX = X & 1;
        const int L0off = bX << 16;          // buffer holding tile X
        const int L1off = (bX ^ 1) << 16;    // buffer holding tile X+1
        int t1 = X + 1; if (t1 >= NTILES) t1 -= NTILES;   // wrap: uniform vmcnt
        int t2 = X + 2; if (t2 >= NTILES) t2 -= NTILES;

        // ---- P1: reads Bb[X], Ahi[X]; stage B0[X+1]; MFMA Alo*Ba ----
#pragma unroll
        for (int ni = 0; ni < 2; ++ni) {
            Bb[ni][0] = LDSREAD(L0off + bRowB + (ni + 2) * 2048 + ck0);
            Bb[ni][1] = LDSREAD(L0off + bRowB + (ni + 2) * 2048 + ck1);
        }
#pragma unroll
        for (int mi = 0; mi < 4; ++mi) {
            Ahi[mi][0] = LDSREAD(L0off + aRowB + (mi + 4) * 2048 + ck0);
            Ahi[mi][1] = LDSREAD(L0off + aRowB + (mi + 4) * 2048 + ck1);
        }
        STAGE_B(0, t1, bX ^ 1);
        MFMA_Q(Alo, Ba, 0, 0);
        PHASE_END(8);

        // ---- P2: stage B1[X+2]; MFMA Alo*Bb ----
        STAGE_B(1, t2, bX);
        MFMA_Q(Alo, Bb, 0, 2);
        PHASE_END(4);

        // ---- P3: read Alo[X+1]; stage A0[X+2]; MFMA Ahi*Ba ----
#pragma unroll
        for (int mi = 0; mi < 4; ++mi) {
            Alo[mi][0] = LDSREAD(L1off + aRowB + mi * 2048 + ck0);
            Alo[mi][1] = LDSREAD(L1off + aRowB + mi * 2048 + ck1);
        }
        STAGE_A(0, t2, bX);
        MFMA_Q(Ahi, Ba, 4, 0);
        PHASE_END(4);

        // ---- P4: read Ba[X+1]; stage A1[X+2]; MFMA Ahi*Bb ----
#pragma unroll
        for (int ni = 0; ni < 2; ++ni) {
            Ba[ni][0] = LDSREAD(L1off + bRowB + ni * 2048 + ck0);
            Ba[ni][1] = LDSREAD(L1off + bRowB + ni * 2048 + ck1);
        }
        STAGE_A(1, t2, bX);
        MFMA_Q(Ahi, Bb, 4, 2);
        PHASE_END(8);
    }

    // ---- epilogue ----
    const int crow0 = m0 + wm * 128 + ((l >> 4) << 2);
    const int ccol0 = n0 + wn * 64 + (l & 15);
    if (MODE == 0) {
        const float* bias = (widx == 0) ? b0 : (widx == 1) ? b1 : b2;
        const int bcol0 = ccol0 - widx * D_;
#pragma unroll
        for (int mi = 0; mi < 8; ++mi)
#pragma unroll
            for (int ni = 0; ni < 4; ++ni) {
                const float bv = bias[bcol0 + ni * 16];
#pragma unroll
                for (int r = 0; r < 4; ++r)
                    outb[(size_t)(crow0 + mi * 16 + r) * NQKV_ + ccol0 + ni * 16] =
                        f2bf(acc[mi][ni][r] + bv);
            }
    } else {
#pragma unroll
        for (int mi = 0; mi < 8; ++mi)
#pragma unroll
            for (int ni = 0; ni < 4; ++ni) {
                const int col = ccol0 + ni * 16;
                const float bv = b0[col];
#pragma unroll
                for (int r = 0; r < 4; ++r) {
                    const size_t idx = (size_t)(crow0 + mi * 16 + r) * D_ + col;
                    outb[idx] = f2bf(acc[mi][ni][r] + bv + bf2f(xres[idx]));
                }
            }
    }
}

// ---------------- local attention: one wave per (m, head-quad) ----------------
__global__ __launch_bounds__(256) void attn_kernel(const u16* __restrict__ QKV,
                                                   const float* __restrict__ bk,
                                                   const float* __restrict__ bv,
                                                   u16* __restrict__ att) {
    const int gw = xcd_swz(blockIdx.x, gridDim.x) * 4 + (threadIdx.x >> 6);
    const int l  = threadIdx.x & 63;
    const int hq = gw % 3;             // head-quad index
    const int m  = gw / 3;
    const int s  = m & (S_ - 1);
    const int col = hq * 256 + l * 4;
    const u16* base = QKV + (size_t)m * NQKV_;

    const u16x4 qv = *(const u16x4*)(base + col);
    float qf[4];
#pragma unroll
    for (int j = 0; j < 4; j++) qf[j] = bf2f(qv[j]);

    float sc[5];
#pragma unroll
    for (int i = 0; i < 5; i++) {
        const int sp = s + i - 2;
        float p;
        if (sp >= 0 && sp < S_) {
            const u16x4 kv = *(const u16x4*)(base + (i - 2) * NQKV_ + D_ + col);
            p = qf[0] * bf2f(kv[0]) + qf[1] * bf2f(kv[1])
              + qf[2] * bf2f(kv[2]) + qf[3] * bf2f(kv[3]);
        } else {
            const float4 kb = *(const float4*)(bk + col);
            p = qf[0] * kb.x + qf[1] * kb.y + qf[2] * kb.z + qf[3] * kb.w;
        }
#pragma unroll
        for (int off = 1; off < 16; off <<= 1) p += __shfl_xor(p, off, 64);
        sc[i] = p * 0.125f;
    }
    float mx = sc[0];
#pragma unroll
    for (int i = 1; i < 5; i++) mx = fmaxf(mx, sc[i]);
    float e[5], sum = 0.f;
#pragma unroll
    for (int i = 0; i < 5; i++) { e[i] = __expf(sc[i] - mx); sum += e[i]; }
    const float inv = 1.f / sum;

    float o[4] = {0.f, 0.f, 0.f, 0.f};
#pragma unroll
    for (int i = 0; i < 5; i++) {
        const float wgt = e[i] * inv;
        const int sp = s + i - 2;
        if (sp >= 0 && sp < S_) {
            const u16x4 vv = *(const u16x4*)(base + (i - 2) * NQKV_ + 2 * D_ + col);
#pragma unroll
            for (int j = 0; j < 4; j++) o[j] += wgt * bf2f(vv[j]);
        } else {
            const float4 vb = *(const float4*)(bv + col);
            o[0] += wgt * vb.x; o[1] += wgt * vb.y;
            o[2] += wgt * vb.z; o[3] += wgt * vb.w;
        }
    }
    u16x4 ov;
#pragma unroll
    for (int j = 0; j < 4; j++) ov[j] = f2bf(o[j]);
    *(u16x4*)(att + (size_t)m * D_ + col) = ov;
}

// ---------------- LayerNorm over rows of 768 (bf16 in, f32 out) ----------------
__global__ __launch_bounds__(256) void ln_kernel(const u16* __restrict__ Yb,
                                                 const float* __restrict__ gamma,
                                                 const float* __restrict__ beta,
                                                 float* __restrict__ out) {
    const int row = blockIdx.x;
    const u16* r = Yb + (size_t)row * D_;
    const int t = threadIdx.x;
    const float v0 = bf2f(r[t]), v1 = bf2f(r[t + 256]), v2 = bf2f(r[t + 512]);
    float s  = v0 + v1 + v2;
    float s2 = v0 * v0 + v1 * v1 + v2 * v2;
#pragma unroll
    for (int off = 32; off > 0; off >>= 1) {
        s  += __shfl_xor(s,  off, 64);
        s2 += __shfl_xor(s2, off, 64);
    }
    __shared__ float red[8];
    const int w = t >> 6, l = t & 63;
    if (l == 0) { red[w] = s; red[4 + w] = s2; }
    __syncthreads();
    s  = red[0] + red[1] + red[2] + red[3];
    s2 = red[4] + red[5] + red[6] + red[7];
    const float mu  = s * (1.f / 768.f);
    const float var = s2 * (1.f / 768.f) - mu * mu;
    const float inv = rsqrtf(var + 1e-5f);
    float* o = out + (size_t)row * D_;
    o[t]       = (v0 - mu) * inv * gamma[t]       + beta[t];
    o[t + 256] = (v1 - mu) * inv * gamma[t + 256] + beta[t + 256];
    o[t + 512] = (v2 - mu) * inv * gamma[t + 512] + beta[t + 512];
}

extern "C" void kernel_launch(void* const* d_in, const int* in_sizes, int n_in,
                              void* d_out, int out_size, void* d_ws, size_t ws_size,
                              hipStream_t stream) {
    const float* x     = (const float*)d_in[0];
    const float* Wq    = (const float*)d_in[1];
    const float* bq    = (const float*)d_in[2];
    const float* Wk    = (const float*)d_in[3];
    const float* bk    = (const float*)d_in[4];
    const float* Wv    = (const float*)d_in[5];
    const float* bv    = (const float*)d_in[6];
    const float* Wo    = (const float*)d_in[7];
    const float* bo    = (const float*)d_in[8];
    const float* gamma = (const float*)d_in[9];
    const float* beta  = (const float*)d_in[10];

    char* ws = (char*)d_ws;
    u16*   Wb  = (u16*)ws;                                  //  4,718,592 B
    u16*   xb  = (u16*)(ws + 4718592);                      // 50,331,648 B (stays live)
    u16*   QKV = (u16*)(ws + 4718592 + 50331648);           // 150,994,944 B
    u16*   yb  = QKV;                                       // reuse after attn
    u16*   att = (u16*)d_out;                               // scratch in d_out

    (void)hipFuncSetAttribute(reinterpret_cast<const void*>(&gemm8_kernel<0>),
                              hipFuncAttributeMaxDynamicSharedMemorySize, 131072);
    (void)hipFuncSetAttribute(reinterpret_cast<const void*>(&gemm8_kernel<1>),
                              hipFuncAttributeMaxDynamicSharedMemorySize, 131072);

    castx_kernel<<<(M_ * D_) / (256 * 4), 256, 0, stream>>>(x, xb);
    wtrans_kernel<<<dim3(24, 24, 4), 256, 0, stream>>>(Wq, Wk, Wv, Wo, Wb);
    gemm8_kernel<0><<<(M_ / 256) * 9, 512, 131072, stream>>>(xb, Wb, bq, bk, bv,
                                                             QKV, nullptr);
    attn_kernel<<<(M_ * 3) / 4, 256, 0, stream>>>(QKV, bk, bv, att);
    gemm8_kernel<1><<<(M_ / 256) * 3, 512, 131072, stream>>>(att, Wb, bo, nullptr, nullptr,
                                                             yb, xb);
    ln_kernel<<<M_, 256, 0, stream>>>(yb, gamma, beta, (float*)d_out);
}

// Round 7
// 327.341 us; speedup vs baseline: 1.5574x; 1.0077x over previous
//
#include <hip/hip_runtime.h>

#define B_  8
#define S_  4096
#define D_  768
#define H_  12
#define M_  (B_ * S_)      // 32768
#define NQKV_ 2304         // 3*D
#define NTILES 12          // 768 / 64

typedef unsigned short u16;
typedef __attribute__((ext_vector_type(4))) float  f32x4;
typedef __attribute__((ext_vector_type(8))) __bf16 bf16x8;
typedef __attribute__((ext_vector_type(4))) u16    u16x4;

#define GAS __attribute__((address_space(1)))
#define LAS __attribute__((address_space(3)))

__device__ __forceinline__ u16 f2bf(float f) {
    unsigned u = __float_as_uint(f);
    u += 0x7FFF + ((u >> 16) & 1);          // round-to-nearest-even
    return (u16)(u >> 16);
}
__device__ __forceinline__ float bf2f(u16 h) {
    return __uint_as_float(((unsigned)h) << 16);
}

__device__ __forceinline__ void gload_lds16(const void* g, void* l) {
    __builtin_amdgcn_global_load_lds((const GAS void*)g, (LAS void*)l, 16, 0, 0);
}

// bijective XCD swizzle (nwg % 8 == 0): each XCD gets a contiguous work chunk
__device__ __forceinline__ int xcd_swz(int bid, int nwg) {
    return (bid & 7) * (nwg >> 3) + (bid >> 3);
}

// ---------------- cast x (f32 -> bf16) ----------------
__global__ __launch_bounds__(256) void castx_kernel(const float* __restrict__ x,
                                                    u16* __restrict__ xb) {
    const int i = blockIdx.x * 256 + threadIdx.x;
    const float4 v = ((const float4*)x)[i];
    u16x4 o;
    o.x = f2bf(v.x); o.y = f2bf(v.y); o.z = f2bf(v.z); o.w = f2bf(v.w);
    ((u16x4*)xb)[i] = o;
}

// ---------------- weight transpose+cast: W[k][n] f32 -> Wb[n][k] bf16 ----------------
__global__ __launch_bounds__(256) void wtrans_kernel(const float* __restrict__ Wq,
                                                     const float* __restrict__ Wk,
                                                     const float* __restrict__ Wv,
                                                     const float* __restrict__ Wo,
                                                     u16* __restrict__ Wb) {
    const float* W = (blockIdx.z == 0) ? Wq : (blockIdx.z == 1) ? Wk
                   : (blockIdx.z == 2) ? Wv : Wo;
    u16* O = Wb + (size_t)blockIdx.z * D_ * D_;
    __shared__ float tile[32][33];
    const int tx = threadIdx.x & 31, ty = threadIdx.x >> 5;  // 32x8
    const int k0 = blockIdx.y * 32, n0 = blockIdx.x * 32;
#pragma unroll
    for (int j = 0; j < 4; j++)
        tile[ty + j * 8][tx] = W[(size_t)(k0 + ty + j * 8) * D_ + n0 + tx];
    __syncthreads();
#pragma unroll
    for (int j = 0; j < 4; j++)
        O[(size_t)(n0 + ty + j * 8) * D_ + k0 + tx] = f2bf(tile[tx][ty + j * 8]);
}

// ============ 256x256 pipelined bf16 MFMA GEMM ============
// 512 threads = 8 waves (2M x 4N), per-wave C = 128x64, BK=64, 12 K-tiles.
// LDS 128 KiB = 2 buffers x (A 256x64 + B 256x64) bf16, XOR-swizzled.
// Fully unrolled K-loop; STAGES WRAP at the tail (t1/t2 mod NTILES) so the
// per-wave vmcnt ledger is IDENTICAL for every tile (R6 lesson: guards that
// skip stages shift what a counted vmcnt retires -> race). Wrapped-stage data
// is never read. Counted vmcnt only at P2-end / P3-end (audited ledger):
//   in-flight after P2 VMBAR(4): B0[X+1],B1[X+2];  after P3 VMBAR(4): B1,A0.
// setprio(1) around MFMA clusters (T5; regime = phase-split schedule).

#define BAR()                                                \
    __builtin_amdgcn_sched_barrier(0);                       \
    __builtin_amdgcn_s_barrier();                            \
    __builtin_amdgcn_sched_barrier(0)

#define VMBAR(N)                                             \
    __builtin_amdgcn_sched_barrier(0);                       \
    asm volatile("s_waitcnt vmcnt(" #N ")" ::: "memory");    \
    __builtin_amdgcn_s_barrier();                            \
    __builtin_amdgcn_sched_barrier(0)

#define MFMA_Q(AF, BF, MO, NO)                                               \
    __builtin_amdgcn_s_setprio(1);                                           \
    _Pragma("unroll") for (int mi = 0; mi < 4; ++mi)                         \
        _Pragma("unroll") for (int ni = 0; ni < 2; ++ni)                     \
            _Pragma("unroll") for (int kh = 0; kh < 2; ++kh)                 \
                acc[mi + MO][ni + NO] =                                      \
                    __builtin_amdgcn_mfma_f32_16x16x32_bf16(                 \
                        AF[mi][kh], BF[ni][kh], acc[mi + MO][ni + NO], 0, 0, 0); \
    __builtin_amdgcn_s_setprio(0)

#define RD(p, imm) (*(const bf16x8*)((p) + (imm)))

template <int MODE>
__global__ __launch_bounds__(512, 2) void gemm8_kernel(
    const u16* __restrict__ A, const u16* __restrict__ Wb,
    const float* __restrict__ b0, const float* __restrict__ b1,
    const float* __restrict__ b2,
    u16* __restrict__ outb, const u16* __restrict__ xres) {
    extern __shared__ char lds[];

    const int t = threadIdx.x;
    const int w = t >> 6, l = t & 63;
    const int wm = w >> 2, wn = w & 3;

    const int NTN = (MODE == 0) ? 9 : 3;
    const int work = xcd_swz(blockIdx.x, gridDim.x);
    const int mt = work / NTN, nt = work % NTN;
    const int m0 = mt * 256;
    const int n0 = nt * 256;
    const int widx = (MODE == 0) ? (n0 / D_) : 3;
    const int n0w = n0 - ((MODE == 0) ? widx * D_ : 0);   // col base within weight

    // ---- staging addresses (pre-swizzled global source) ----
    const int srow   = t >> 3;                       // 0..63
    const int schunk = (t & 7) ^ (srow & 7);         // swizzled 16B chunk 0..7
    const u16* Asrc = A + (size_t)(m0 + srow) * D_ + schunk * 8;
    const u16* Bsrc = Wb + (size_t)widx * (D_ * D_) + (size_t)(n0w + srow) * D_ + schunk * 8;

    // half-tile stage: 128 rows x 64 cols = 2 x global_load_lds(16B) per wave
    auto STAGE_A = [&](int h, int tk, int db) {
        const u16* s = Asrc + (size_t)(h * 128) * D_ + tk * 64;
        char* d = lds + db * 65536 + h * 16384 + (w << 10);
        gload_lds16(s, d);
        gload_lds16(s + 64 * D_, d + 8192);
    };
    auto STAGE_B = [&](int h, int tk, int db) {
        const u16* s = Bsrc + (size_t)(h * 128) * D_ + tk * 64;
        char* d = lds + db * 65536 + 32768 + h * 16384 + (w << 10);
        gload_lds16(s, d);
        gload_lds16(s + 64 * D_, d + 8192);
    };

    // ---- fragment read bases (swizzled); ds_read = base + compile-time imm ----
    const int ck0 = (((l >> 4) ^ (l & 7)) << 4);
    const int ck1 = ((((l >> 4) + 4) ^ (l & 7)) << 4);
    const int aRowB = (wm * 128 + (l & 15)) * 128;            // byte in A region
    const int bRowB = 32768 + (wn * 64 + (l & 15)) * 128;     // byte in B region
    const char* aC0[2] = { lds + aRowB + ck0, lds + 65536 + aRowB + ck0 };
    const char* aC1[2] = { lds + aRowB + ck1, lds + 65536 + aRowB + ck1 };
    const char* bC0[2] = { lds + bRowB + ck0, lds + 65536 + bRowB + ck0 };
    const char* bC1[2] = { lds + bRowB + ck1, lds + 65536 + bRowB + ck1 };

    f32x4 acc[8][4];
#pragma unroll
    for (int i = 0; i < 8; i++)
#pragma unroll
        for (int j = 0; j < 4; j++) acc[i][j] = (f32x4){0.f, 0.f, 0.f, 0.f};

    bf16x8 Alo[4][2], Ahi[4][2], Ba[2][2], Bb[2][2];

    // ---- prologue: tile0 (8 loads) then B1[1],A0[1],A1[1] (6 loads) ----
    STAGE_A(0, 0, 0); STAGE_A(1, 0, 0); STAGE_B(0, 0, 0); STAGE_B(1, 0, 0);
    STAGE_B(1, 1, 1); STAGE_A(0, 1, 1); STAGE_A(1, 1, 1);
    __builtin_amdgcn_sched_barrier(0);
    asm volatile("s_waitcnt vmcnt(6)" ::: "memory");   // tile0 fully landed
    __builtin_amdgcn_s_barrier();
    __builtin_amdgcn_sched_barrier(0);
    // preload regs for tile 0 (buf0)
#pragma unroll
    for (int mi = 0; mi < 4; ++mi) {
        Alo[mi][0] = RD(aC0[0], mi * 2048);
        Alo[mi][1] = RD(aC1[0], mi * 2048);
    }
#pragma unroll
    for (int ni = 0; ni < 2; ++ni) {
        Ba[ni][0] = RD(bC0[0], ni * 2048);
        Ba[ni][1] = RD(bC1[0], ni * 2048);
    }

#pragma unroll
    for (int X = 0; X < NTILES; ++X) {
        const int c = X & 1;         // buffer holding tile X
        const int o = c ^ 1;         // buffer holding tile X+1
        // WRAPPED stage indices: keep vmcnt ledger uniform at the tail.
        const int t1 = (X + 1 < NTILES) ? X + 1 : X + 1 - NTILES;
        const int t2 = (X + 2 < NTILES) ? X + 2 : X + 2 - NTILES;

        // ---- P1: read Bb[X], Ahi[X]; stage B0[t1]->o; MFMA Alo*Ba ----
#pragma unroll
        for (int ni = 0; ni < 2; ++ni) {
            Bb[ni][0] = RD(bC0[c], (ni + 2) * 2048);
            Bb[ni][1] = RD(bC1[c], (ni + 2) * 2048);
        }
#pragma unroll
        for (int mi = 0; mi < 4; ++mi) {
            Ahi[mi][0] = RD(aC0[c], (mi + 4) * 2048);
            Ahi[mi][1] = RD(aC1[c], (mi + 4) * 2048);
        }
        STAGE_B(0, t1, o);
        MFMA_Q(Alo, Ba, 0, 0);
        BAR();

        // ---- P2: stage B1[t2]->c; MFMA Alo*Bb ----
        STAGE_B(1, t2, c);
        MFMA_Q(Alo, Bb, 0, 2);
        VMBAR(4);

        // ---- P3: read Alo[X+1]; stage A0[t2]->c; MFMA Ahi*Ba ----
        if (X + 1 < NTILES) {
#pragma unroll
            for (int mi = 0; mi < 4; ++mi) {
                Alo[mi][0] = RD(aC0[o], mi * 2048);
                Alo[mi][1] = RD(aC1[o], mi * 2048);
            }
        }
        STAGE_A(0, t2, c);
        MFMA_Q(Ahi, Ba, 4, 0);
        VMBAR(4);

        // ---- P4: read Ba[X+1]; stage A1[t2]->c; MFMA Ahi*Bb ----
        if (X + 1 < NTILES) {
#pragma unroll
            for (int ni = 0; ni < 2; ++ni) {
                Ba[ni][0] = RD(bC0[o], ni * 2048);
                Ba[ni][1] = RD(bC1[o], ni * 2048);
            }
        }
        STAGE_A(1, t2, c);
        MFMA_Q(Ahi, Bb, 4, 2);
        BAR();
    }

    // ---- epilogue ----
    const int crow0 = m0 + wm * 128 + ((l >> 4) << 2);
    const int ccol0 = n0 + wn * 64 + (l & 15);
    if (MODE == 0) {
        const float* bias = (widx == 0) ? b0 : (widx == 1) ? b1 : b2;
        const int bcol0 = ccol0 - widx * D_;
#pragma unroll
        for (int mi = 0; mi < 8; ++mi)
#pragma unroll
            for (int ni = 0; ni < 4; ++ni) {
                const float bv = bias[bcol0 + ni * 16];
#pragma unroll
                for (int r = 0; r < 4; ++r)
                    outb[(size_t)(crow0 + mi * 16 + r) * NQKV_ + ccol0 + ni * 16] =
                        f2bf(acc[mi][ni][r] + bv);
            }
    } else {
#pragma unroll
        for (int mi = 0; mi < 8; ++mi)
#pragma unroll
            for (int ni = 0; ni < 4; ++ni) {
                const int col = ccol0 + ni * 16;
                const float bv = b0[col];
#pragma unroll
                for (int r = 0; r < 4; ++r) {
                    const size_t idx = (size_t)(crow0 + mi * 16 + r) * D_ + col;
                    outb[idx] = f2bf(acc[mi][ni][r] + bv + bf2f(xres[idx]));
                }
            }
    }
}

// ---------------- local attention: one wave per (m, head-quad) ----------------
__global__ __launch_bounds__(256) void attn_kernel(const u16* __restrict__ QKV,
                                                   const float* __restrict__ bk,
                                                   const float* __restrict__ bv,
                                                   u16* __restrict__ att) {
    const int gw = xcd_swz(blockIdx.x, gridDim.x) * 4 + (threadIdx.x >> 6);
    const int l  = threadIdx.x & 63;
    const int hq = gw % 3;             // head-quad index
    const int m  = gw / 3;
    const int s  = m & (S_ - 1);
    const int col = hq * 256 + l * 4;
    const u16* base = QKV + (size_t)m * NQKV_;

    const u16x4 qv = *(const u16x4*)(base + col);
    float qf[4];
#pragma unroll
    for (int j = 0; j < 4; j++) qf[j] = bf2f(qv[j]);

    float sc[5];
#pragma unroll
    for (int i = 0; i < 5; i++) {
        const int sp = s + i - 2;
        float p;
        if (sp >= 0 && sp < S_) {
            const u16x4 kv = *(const u16x4*)(base + (i - 2) * NQKV_ + D_ + col);
            p = qf[0] * bf2f(kv[0]) + qf[1] * bf2f(kv[1])
              + qf[2] * bf2f(kv[2]) + qf[3] * bf2f(kv[3]);
        } else {
            const float4 kb = *(const float4*)(bk + col);
            p = qf[0] * kb.x + qf[1] * kb.y + qf[2] * kb.z + qf[3] * kb.w;
        }
#pragma unroll
        for (int off = 1; off < 16; off <<= 1) p += __shfl_xor(p, off, 64);
        sc[i] = p * 0.125f;
    }
    float mx = sc[0];
#pragma unroll
    for (int i = 1; i < 5; i++) mx = fmaxf(mx, sc[i]);
    float e[5], sum = 0.f;
#pragma unroll
    for (int i = 0; i < 5; i++) { e[i] = __expf(sc[i] - mx); sum += e[i]; }
    const float inv = 1.f / sum;

    float o[4] = {0.f, 0.f, 0.f, 0.f};
#pragma unroll
    for (int i = 0; i < 5; i++) {
        const float wgt = e[i] * inv;
        const int sp = s + i - 2;
        if (sp >= 0 && sp < S_) {
            const u16x4 vv = *(const u16x4*)(base + (i - 2) * NQKV_ + 2 * D_ + col);
#pragma unroll
            for (int j = 0; j < 4; j++) o[j] += wgt * bf2f(vv[j]);
        } else {
            const float4 vb = *(const float4*)(bv + col);
            o[0] += wgt * vb.x; o[1] += wgt * vb.y;
            o[2] += wgt * vb.z; o[3] += wgt * vb.w;
        }
    }
    u16x4 ov;
#pragma unroll
    for (int j = 0; j < 4; j++) ov[j] = f2bf(o[j]);
    *(u16x4*)(att + (size_t)m * D_ + col) = ov;
}

// ---------------- LayerNorm over rows of 768 (bf16 in, f32 out) ----------------
__global__ __launch_bounds__(256) void ln_kernel(const u16* __restrict__ Yb,
                                                 const float* __restrict__ gamma,
                                                 const float* __restrict__ beta,
                                                 float* __restrict__ out) {
    const int row = blockIdx.x;
    const u16* r = Yb + (size_t)row * D_;
    const int t = threadIdx.x;
    const float v0 = bf2f(r[t]), v1 = bf2f(r[t + 256]), v2 = bf2f(r[t + 512]);
    float s  = v0 + v1 + v2;
    float s2 = v0 * v0 + v1 * v1 + v2 * v2;
#pragma unroll
    for (int off = 32; off > 0; off >>= 1) {
        s  += __shfl_xor(s,  off, 64);
        s2 += __shfl_xor(s2, off, 64);
    }
    __shared__ float red[8];
    const int w = t >> 6, l = t & 63;
    if (l == 0) { red[w] = s; red[4 + w] = s2; }
    __syncthreads();
    s  = red[0] + red[1] + red[2] + red[3];
    s2 = red[4] + red[5] + red[6] + red[7];
    const float mu  = s * (1.f / 768.f);
    const float var = s2 * (1.f / 768.f) - mu * mu;
    const float inv = rsqrtf(var + 1e-5f);
    float* o = out + (size_t)row * D_;
    o[t]       = (v0 - mu) * inv * gamma[t]       + beta[t];
    o[t + 256] = (v1 - mu) * inv * gamma[t + 256] + beta[t + 256];
    o[t + 512] = (v2 - mu) * inv * gamma[t + 512] + beta[t + 512];
}

extern "C" void kernel_launch(void* const* d_in, const int* in_sizes, int n_in,
                              void* d_out, int out_size, void* d_ws, size_t ws_size,
                              hipStream_t stream) {
    const float* x     = (const float*)d_in[0];
    const float* Wq    = (const float*)d_in[1];
    const float* bq    = (const float*)d_in[2];
    const float* Wk    = (const float*)d_in[3];
    const float* bk    = (const float*)d_in[4];
    const float* Wv    = (const float*)d_in[5];
    const float* bv    = (const float*)d_in[6];
    const float* Wo    = (const float*)d_in[7];
    const float* bo    = (const float*)d_in[8];
    const float* gamma = (const float*)d_in[9];
    const float* beta  = (const float*)d_in[10];

    char* ws = (char*)d_ws;
    u16*   Wb  = (u16*)ws;                                  //  4,718,592 B
    u16*   xb  = (u16*)(ws + 4718592);                      // 50,331,648 B (stays live)
    u16*   QKV = (u16*)(ws + 4718592 + 50331648);           // 150,994,944 B
    u16*   yb  = QKV;                                       // reuse after attn
    u16*   att = (u16*)d_out;                               // scratch in d_out

    (void)hipFuncSetAttribute(reinterpret_cast<const void*>(&gemm8_kernel<0>),
                              hipFuncAttributeMaxDynamicSharedMemorySize, 131072);
    (void)hipFuncSetAttribute(reinterpret_cast<const void*>(&gemm8_kernel<1>),
                              hipFuncAttributeMaxDynamicSharedMemorySize, 131072);

    castx_kernel<<<(M_ * D_) / (256 * 4), 256, 0, stream>>>(x, xb);
    wtrans_kernel<<<dim3(24, 24, 4), 256, 0, stream>>>(Wq, Wk, Wv, Wo, Wb);
    gemm8_kernel<0><<<(M_ / 256) * 9, 512, 131072, stream>>>(xb, Wb, bq, bk, bv,
                                                             QKV, nullptr);
    attn_kernel<<<(M_ * 3) / 4, 256, 0, stream>>>(QKV, bk, bv, att);
    gemm8_kernel<1><<<(M_ / 256) * 3, 512, 131072, stream>>>(att, Wb, bo, nullptr, nullptr,
                                                             yb, xb);
    ln_kernel<<<M_, 256, 0, stream>>>(yb, gamma, beta, (float*)d_out);
}

// Round 8
// 300.920 us; speedup vs baseline: 1.6942x; 1.0878x over previous
//
#include <hip/hip_runtime.h>

#define B_  8
#define S_  4096
#define D_  768
#define H_  12
#define M_  (B_ * S_)      // 32768
#define NQKV_ 2304         // 3*D
#define NTILES 12          // 768 / 64

typedef unsigned short u16;
typedef __attribute__((ext_vector_type(4))) float  f32x4;
typedef __attribute__((ext_vector_type(8))) __bf16 bf16x8;
typedef __attribute__((ext_vector_type(4))) u16    u16x4;

#define GAS __attribute__((address_space(1)))
#define LAS __attribute__((address_space(3)))

__device__ __forceinline__ u16 f2bf(float f) {
    unsigned u = __float_as_uint(f);
    u += 0x7FFF + ((u >> 16) & 1);          // round-to-nearest-even
    return (u16)(u >> 16);
}
__device__ __forceinline__ float bf2f(u16 h) {
    return __uint_as_float(((unsigned)h) << 16);
}

__device__ __forceinline__ void gload_lds16(const void* g, void* l) {
    __builtin_amdgcn_global_load_lds((const GAS void*)g, (LAS void*)l, 16, 0, 0);
}

// bijective XCD swizzle (nwg % 8 == 0): each XCD gets a contiguous work chunk
__device__ __forceinline__ int xcd_swz(int bid, int nwg) {
    return (bid & 7) * (nwg >> 3) + (bid >> 3);
}

// ---------------- cast x (f32 -> bf16) ----------------
__global__ __launch_bounds__(256) void castx_kernel(const float* __restrict__ x,
                                                    u16* __restrict__ xb) {
    const int i = blockIdx.x * 256 + threadIdx.x;
    const float4 v = ((const float4*)x)[i];
    u16x4 o;
    o.x = f2bf(v.x); o.y = f2bf(v.y); o.z = f2bf(v.z); o.w = f2bf(v.w);
    ((u16x4*)xb)[i] = o;
}

// ---------------- weight transpose+cast: W[k][n] f32 -> Wb[n][k] bf16 ----------------
__global__ __launch_bounds__(256) void wtrans_kernel(const float* __restrict__ Wq,
                                                     const float* __restrict__ Wk,
                                                     const float* __restrict__ Wv,
                                                     const float* __restrict__ Wo,
                                                     u16* __restrict__ Wb) {
    const float* W = (blockIdx.z == 0) ? Wq : (blockIdx.z == 1) ? Wk
                   : (blockIdx.z == 2) ? Wv : Wo;
    u16* O = Wb + (size_t)blockIdx.z * D_ * D_;
    __shared__ float tile[32][33];
    const int tx = threadIdx.x & 31, ty = threadIdx.x >> 5;  // 32x8
    const int k0 = blockIdx.y * 32, n0 = blockIdx.x * 32;
#pragma unroll
    for (int j = 0; j < 4; j++)
        tile[ty + j * 8][tx] = W[(size_t)(k0 + ty + j * 8) * D_ + n0 + tx];
    __syncthreads();
#pragma unroll
    for (int j = 0; j < 4; j++)
        O[(size_t)(n0 + ty + j * 8) * D_ + k0 + tx] = f2bf(tile[tx][ty + j * 8]);
}

// ============ 256x256 8-phase bf16 MFMA GEMM (faithful m201 template) ============
// 512 threads = 8 waves (2M x 4N), per-wave C = 128x64, BK=64, 12 K-tiles.
// LDS 128 KiB = 2 buffers x (A 256x64 + B 256x64) bf16, XOR-swizzled (st-16B).
// SAME-PHASE reads: each phase {ds_read subtile ; stage 1 half-tile ;
//   [lgkm(8) if 12 reads] ; s_barrier ; lgkm(0) ; setprio1 ; 16 MFMA ;
//   setprio0 ; [vmcnt(4) at ph4] ; s_barrier}.
// Region ledger (per tile X, buf c=X&1, o=c^1):
//  reads: ph1 Alo+Ba(12), ph2 Bb(4), ph3 Ahi(8), ph4 none.
//  A-half h last read ph3 (wm=h waves); B-half last read ph2.
//  stages: ph1 A0(X+1)->o, ph2 A1(X+1)->o, ph3 B0(X+2)->c, ph4 B1(X+2)->c.
//  WAR: each stage >=1 phase after the region's last drained read.  RAW:
//  vmcnt(4) at ph4-end leaves only {B0,B1}(X+2) in flight -> X+1 fully landed.

#define PH_IN()                                              \
    __builtin_amdgcn_sched_barrier(0);                       \
    __builtin_amdgcn_s_barrier();                            \
    asm volatile("s_waitcnt lgkmcnt(0)" ::: "memory");       \
    __builtin_amdgcn_sched_barrier(0)

#define PH_OUT()                                             \
    __builtin_amdgcn_sched_barrier(0);                       \
    __builtin_amdgcn_s_barrier();                            \
    __builtin_amdgcn_sched_barrier(0)

#define PH_OUT_VM(N)                                         \
    __builtin_amdgcn_sched_barrier(0);                       \
    asm volatile("s_waitcnt vmcnt(" #N ")" ::: "memory");    \
    __builtin_amdgcn_s_barrier();                            \
    __builtin_amdgcn_sched_barrier(0)

#define MFMA_Q(AF, BF, MO, NO)                                               \
    __builtin_amdgcn_s_setprio(1);                                           \
    _Pragma("unroll") for (int mi = 0; mi < 4; ++mi)                         \
        _Pragma("unroll") for (int ni = 0; ni < 2; ++ni)                     \
            _Pragma("unroll") for (int kh = 0; kh < 2; ++kh)                 \
                acc[mi + MO][ni + NO] =                                      \
                    __builtin_amdgcn_mfma_f32_16x16x32_bf16(                 \
                        AF[mi][kh], BF[ni][kh], acc[mi + MO][ni + NO], 0, 0, 0); \
    __builtin_amdgcn_s_setprio(0)

#define RD(p, imm) (*(const bf16x8*)((p) + (imm)))

template <int MODE>
__global__ __launch_bounds__(512, 2) void gemm8_kernel(
    const u16* __restrict__ A, const u16* __restrict__ Wb,
    const float* __restrict__ b0, const float* __restrict__ b1,
    const float* __restrict__ b2,
    u16* __restrict__ outb, const u16* __restrict__ xres) {
    extern __shared__ char lds[];

    const int t = threadIdx.x;
    const int w = t >> 6, l = t & 63;
    const int wm = w >> 2, wn = w & 3;

    const int NTN = (MODE == 0) ? 9 : 3;
    const int work = xcd_swz(blockIdx.x, gridDim.x);
    const int mt = work / NTN, nt = work % NTN;
    const int m0 = mt * 256;
    const int n0 = nt * 256;
    const int widx = (MODE == 0) ? (n0 / D_) : 3;
    const int n0w = n0 - ((MODE == 0) ? widx * D_ : 0);   // col base within weight

    // ---- staging addresses (pre-swizzled global source) ----
    const int srow   = t >> 3;                       // 0..63
    const int schunk = (t & 7) ^ (srow & 7);         // swizzled 16B chunk 0..7
    const u16* Asrc = A + (size_t)(m0 + srow) * D_ + schunk * 8;
    const u16* Bsrc = Wb + (size_t)widx * (D_ * D_) + (size_t)(n0w + srow) * D_ + schunk * 8;

    // half-tile stage: 128 rows x 64 cols = 2 x global_load_lds(16B) per wave
    auto STAGE_A = [&](int h, int tk, int db) {
        const u16* s = Asrc + (size_t)(h * 128) * D_ + tk * 64;
        char* d = lds + db * 65536 + h * 16384 + (w << 10);
        gload_lds16(s, d);
        gload_lds16(s + 64 * D_, d + 8192);
    };
    auto STAGE_B = [&](int h, int tk, int db) {
        const u16* s = Bsrc + (size_t)(h * 128) * D_ + tk * 64;
        char* d = lds + db * 65536 + 32768 + h * 16384 + (w << 10);
        gload_lds16(s, d);
        gload_lds16(s + 64 * D_, d + 8192);
    };

    // ---- fragment read bases (swizzled); ds_read = base + compile-time imm ----
    const int ck0 = (((l >> 4) ^ (l & 7)) << 4);
    const int ck1 = ((((l >> 4) + 4) ^ (l & 7)) << 4);
    const int aRowB = (wm * 128 + (l & 15)) * 128;            // byte in A region
    const int bRowB = 32768 + (wn * 64 + (l & 15)) * 128;     // byte in B region
    const char* aC0[2] = { lds + aRowB + ck0, lds + 65536 + aRowB + ck0 };
    const char* aC1[2] = { lds + aRowB + ck1, lds + 65536 + aRowB + ck1 };
    const char* bC0[2] = { lds + bRowB + ck0, lds + 65536 + bRowB + ck0 };
    const char* bC1[2] = { lds + bRowB + ck1, lds + 65536 + bRowB + ck1 };

    f32x4 acc[8][4];
#pragma unroll
    for (int i = 0; i < 8; i++)
#pragma unroll
        for (int j = 0; j < 4; j++) acc[i][j] = (f32x4){0.f, 0.f, 0.f, 0.f};

    bf16x8 Alo[4][2], Ahi[4][2], Ba[2][2], Bb[2][2];

    // ---- prologue: A0,A1,B0,B1 of tile0 + B0,B1 of tile1 (12 loads) ----
    STAGE_A(0, 0, 0); STAGE_A(1, 0, 0); STAGE_B(0, 0, 0); STAGE_B(1, 0, 0);
    STAGE_B(0, 1, 1); STAGE_B(1, 1, 1);
    __builtin_amdgcn_sched_barrier(0);
    asm volatile("s_waitcnt vmcnt(4)" ::: "memory");   // tile0 landed; B(1) in flight
    __builtin_amdgcn_s_barrier();
    __builtin_amdgcn_sched_barrier(0);

#pragma unroll
    for (int X = 0; X < NTILES; ++X) {
        const int c = X & 1;         // buffer holding tile X
        const int o = c ^ 1;         // buffer holding tile X+1
        // wrapped stage indices: uniform vmcnt ledger at the tail (R6 lesson);
        // wrapped-stage data is never read.
        const int t1 = (X + 1 < NTILES) ? X + 1 : X + 1 - NTILES;
        const int t2 = (X + 2 < NTILES) ? X + 2 : X + 2 - NTILES;

        // ---- ph1: read Alo,Ba (12); stage A0(t1)->o; MFMA Alo*Ba ----
#pragma unroll
        for (int mi = 0; mi < 4; ++mi) {
            Alo[mi][0] = RD(aC0[c], mi * 2048);
            Alo[mi][1] = RD(aC1[c], mi * 2048);
        }
#pragma unroll
        for (int ni = 0; ni < 2; ++ni) {
            Ba[ni][0] = RD(bC0[c], ni * 2048);
            Ba[ni][1] = RD(bC1[c], ni * 2048);
        }
        STAGE_A(0, t1, o);
        asm volatile("s_waitcnt lgkmcnt(8)" ::: "memory");
        PH_IN();
        MFMA_Q(Alo, Ba, 0, 0);
        PH_OUT();

        // ---- ph2: read Bb (4); stage A1(t1)->o; MFMA Alo*Bb ----
#pragma unroll
        for (int ni = 0; ni < 2; ++ni) {
            Bb[ni][0] = RD(bC0[c], (ni + 2) * 2048);
            Bb[ni][1] = RD(bC1[c], (ni + 2) * 2048);
        }
        STAGE_A(1, t1, o);
        PH_IN();
        MFMA_Q(Alo, Bb, 0, 2);
        PH_OUT();

        // ---- ph3: read Ahi (8); stage B0(t2)->c; MFMA Ahi*Ba ----
#pragma unroll
        for (int mi = 0; mi < 4; ++mi) {
            Ahi[mi][0] = RD(aC0[c], (mi + 4) * 2048);
            Ahi[mi][1] = RD(aC1[c], (mi + 4) * 2048);
        }
        STAGE_B(0, t2, c);
        PH_IN();
        MFMA_Q(Ahi, Ba, 4, 0);
        PH_OUT();

        // ---- ph4: no reads; stage B1(t2)->c; MFMA Ahi*Bb; vmcnt(4) ----
        STAGE_B(1, t2, c);
        PH_IN();
        MFMA_Q(Ahi, Bb, 4, 2);
        PH_OUT_VM(4);
    }

    // drain wrapped stages before exit (DMA must not outlive the block)
    asm volatile("s_waitcnt vmcnt(0)" ::: "memory");

    // ---- epilogue ----
    const int crow0 = m0 + wm * 128 + ((l >> 4) << 2);
    const int ccol0 = n0 + wn * 64 + (l & 15);
    if (MODE == 0) {
        const float* bias = (widx == 0) ? b0 : (widx == 1) ? b1 : b2;
        const int bcol0 = ccol0 - widx * D_;
#pragma unroll
        for (int mi = 0; mi < 8; ++mi)
#pragma unroll
            for (int ni = 0; ni < 4; ++ni) {
                const float bv = bias[bcol0 + ni * 16];
#pragma unroll
                for (int r = 0; r < 4; ++r)
                    outb[(size_t)(crow0 + mi * 16 + r) * NQKV_ + ccol0 + ni * 16] =
                        f2bf(acc[mi][ni][r] + bv);
            }
    } else {
#pragma unroll
        for (int mi = 0; mi < 8; ++mi)
#pragma unroll
            for (int ni = 0; ni < 4; ++ni) {
                const int col = ccol0 + ni * 16;
                const float bv = b0[col];
#pragma unroll
                for (int r = 0; r < 4; ++r) {
                    const size_t idx = (size_t)(crow0 + mi * 16 + r) * D_ + col;
                    outb[idx] = f2bf(acc[mi][ni][r] + bv + bf2f(xres[idx]));
                }
            }
    }
}

// ---------------- local attention: one wave per (m, head-quad) ----------------
__global__ __launch_bounds__(256) void attn_kernel(const u16* __restrict__ QKV,
                                                   const float* __restrict__ bk,
                                                   const float* __restrict__ bv,
                                                   u16* __restrict__ att) {
    const int gw = xcd_swz(blockIdx.x, gridDim.x) * 4 + (threadIdx.x >> 6);
    const int l  = threadIdx.x & 63;
    const int hq = gw % 3;             // head-quad index
    const int m  = gw / 3;
    const int s  = m & (S_ - 1);
    const int col = hq * 256 + l * 4;
    const u16* base = QKV + (size_t)m * NQKV_;

    const u16x4 qv = *(const u16x4*)(base + col);
    float qf[4];
#pragma unroll
    for (int j = 0; j < 4; j++) qf[j] = bf2f(qv[j]);

    float sc[5];
#pragma unroll
    for (int i = 0; i < 5; i++) {
        const int sp = s + i - 2;
        float p;
        if (sp >= 0 && sp < S_) {
            const u16x4 kv = *(const u16x4*)(base + (i - 2) * NQKV_ + D_ + col);
            p = qf[0] * bf2f(kv[0]) + qf[1] * bf2f(kv[1])
              + qf[2] * bf2f(kv[2]) + qf[3] * bf2f(kv[3]);
        } else {
            const float4 kb = *(const float4*)(bk + col);
            p = qf[0] * kb.x + qf[1] * kb.y + qf[2] * kb.z + qf[3] * kb.w;
        }
#pragma unroll
        for (int off = 1; off < 16; off <<= 1) p += __shfl_xor(p, off, 64);
        sc[i] = p * 0.125f;
    }
    float mx = sc[0];
#pragma unroll
    for (int i = 1; i < 5; i++) mx = fmaxf(mx, sc[i]);
    float e[5], sum = 0.f;
#pragma unroll
    for (int i = 0; i < 5; i++) { e[i] = __expf(sc[i] - mx); sum += e[i]; }
    const float inv = 1.f / sum;

    float o[4] = {0.f, 0.f, 0.f, 0.f};
#pragma unroll
    for (int i = 0; i < 5; i++) {
        const float wgt = e[i] * inv;
        const int sp = s + i - 2;
        if (sp >= 0 && sp < S_) {
            const u16x4 vv = *(const u16x4*)(base + (i - 2) * NQKV_ + 2 * D_ + col);
#pragma unroll
            for (int j = 0; j < 4; j++) o[j] += wgt * bf2f(vv[j]);
        } else {
            const float4 vb = *(const float4*)(bv + col);
            o[0] += wgt * vb.x; o[1] += wgt * vb.y;
            o[2] += wgt * vb.z; o[3] += wgt * vb.w;
        }
    }
    u16x4 ov;
#pragma unroll
    for (int j = 0; j < 4; j++) ov[j] = f2bf(o[j]);
    *(u16x4*)(att + (size_t)m * D_ + col) = ov;
}

// ---------------- LayerNorm over rows of 768 (bf16 in, f32 out) ----------------
__global__ __launch_bounds__(256) void ln_kernel(const u16* __restrict__ Yb,
                                                 const float* __restrict__ gamma,
                                                 const float* __restrict__ beta,
                                                 float* __restrict__ out) {
    const int row = blockIdx.x;
    const u16* r = Yb + (size_t)row * D_;
    const int t = threadIdx.x;
    const float v0 = bf2f(r[t]), v1 = bf2f(r[t + 256]), v2 = bf2f(r[t + 512]);
    float s  = v0 + v1 + v2;
    float s2 = v0 * v0 + v1 * v1 + v2 * v2;
#pragma unroll
    for (int off = 32; off > 0; off >>= 1) {
        s  += __shfl_xor(s,  off, 64);
        s2 += __shfl_xor(s2, off, 64);
    }
    __shared__ float red[8];
    const int w = t >> 6, l = t & 63;
    if (l == 0) { red[w] = s; red[4 + w] = s2; }
    __syncthreads();
    s  = red[0] + red[1] + red[2] + red[3];
    s2 = red[4] + red[5] + red[6] + red[7];
    const float mu  = s * (1.f / 768.f);
    const float var = s2 * (1.f / 768.f) - mu * mu;
    const float inv = rsqrtf(var + 1e-5f);
    float* o = out + (size_t)row * D_;
    o[t]       = (v0 - mu) * inv * gamma[t]       + beta[t];
    o[t + 256] = (v1 - mu) * inv * gamma[t + 256] + beta[t + 256];
    o[t + 512] = (v2 - mu) * inv * gamma[t + 512] + beta[t + 512];
}

extern "C" void kernel_launch(void* const* d_in, const int* in_sizes, int n_in,
                              void* d_out, int out_size, void* d_ws, size_t ws_size,
                              hipStream_t stream) {
    const float* x     = (const float*)d_in[0];
    const float* Wq    = (const float*)d_in[1];
    const float* bq    = (const float*)d_in[2];
    const float* Wk    = (const float*)d_in[3];
    const float* bk    = (const float*)d_in[4];
    const float* Wv    = (const float*)d_in[5];
    const float* bv    = (const float*)d_in[6];
    const float* Wo    = (const float*)d_in[7];
    const float* bo    = (const float*)d_in[8];
    const float* gamma = (const float*)d_in[9];
    const float* beta  = (const float*)d_in[10];

    char* ws = (char*)d_ws;
    u16*   Wb  = (u16*)ws;                                  //  4,718,592 B
    u16*   xb  = (u16*)(ws + 4718592);                      // 50,331,648 B (stays live)
    u16*   QKV = (u16*)(ws + 4718592 + 50331648);           // 150,994,944 B
    u16*   yb  = QKV;                                       // reuse after attn
    u16*   att = (u16*)d_out;                               // scratch in d_out

    (void)hipFuncSetAttribute(reinterpret_cast<const void*>(&gemm8_kernel<0>),
                              hipFuncAttributeMaxDynamicSharedMemorySize, 131072);
    (void)hipFuncSetAttribute(reinterpret_cast<const void*>(&gemm8_kernel<1>),
                              hipFuncAttributeMaxDynamicSharedMemorySize, 131072);

    castx_kernel<<<(M_ * D_) / (256 * 4), 256, 0, stream>>>(x, xb);
    wtrans_kernel<<<dim3(24, 24, 4), 256, 0, stream>>>(Wq, Wk, Wv, Wo, Wb);
    gemm8_kernel<0><<<(M_ / 256) * 9, 512, 131072, stream>>>(xb, Wb, bq, bk, bv,
                                                             QKV, nullptr);
    attn_kernel<<<(M_ * 3) / 4, 256, 0, stream>>>(QKV, bk, bv, att);
    gemm8_kernel<1><<<(M_ / 256) * 3, 512, 131072, stream>>>(att, Wb, bo, nullptr, nullptr,
                                                             yb, xb);
    ln_kernel<<<M_, 256, 0, stream>>>(yb, gamma, beta, (float*)d_out);
}